// Round 2
// baseline (1469.249 us; speedup 1.0000x reference)
//
#include <hip/hip_runtime.h>

// TransformerLayer on MI355X: 2x self-block (shared weights, batched) + cross-block.
// All activations bf16 for MFMA GEMMs, fp32 accumulate, fp32 residual path.
// B=2, N=2048, D=1024, H=16, HD=64 -> M = 2*B*N = 8192 rows everywhere.
// Workspace budget kept < 192 MiB (round-1 crash suspect: ws overflow).

typedef unsigned short u16;
typedef float f32x4 __attribute__((ext_vector_type(4)));
typedef __bf16 bf16x8 __attribute__((ext_vector_type(8)));
typedef u16 u16x2 __attribute__((ext_vector_type(2)));
typedef u16 u16x4 __attribute__((ext_vector_type(4)));
typedef u16 u16x8 __attribute__((ext_vector_type(8)));

__device__ __forceinline__ u16 f2b(float f) {
  union { float f; unsigned u; } v; v.f = f;
  unsigned r = v.u + 0x7FFFu + ((v.u >> 16) & 1u);  // RNE
  return (u16)(r >> 16);
}
__device__ __forceinline__ float b2f(u16 s) {
  union { unsigned u; float f; } v; v.u = ((unsigned)s) << 16;
  return v.f;
}
__device__ __forceinline__ void gload16(const void* g, void* l) {
  __builtin_amdgcn_global_load_lds((const __attribute__((address_space(1))) void*)g,
                                   (__attribute__((address_space(3))) void*)l, 16, 0, 0);
}
#define MFMA16(a, b, c) __builtin_amdgcn_mfma_f32_16x16x32_bf16(a, b, c, 0, 0, 0)

// ---------------------------------------------------------------------------
// Weight prep: fp32 [K][N] -> bf16 [N][K] (B^T layout for the GEMM)
// ---------------------------------------------------------------------------
__global__ __launch_bounds__(256) void wtrans(const float* __restrict__ src,
                                              u16* __restrict__ dst, int K, int N) {
  __shared__ __align__(16) u16 tile[64][72];
  const int k0 = blockIdx.y * 64, n0 = blockIdx.x * 64;
  const int t = threadIdx.x;
  {
    const int kl = t >> 2, nc = (t & 3) * 16;
    const float* sp = src + (size_t)(k0 + kl) * N + n0 + nc;
#pragma unroll
    for (int j = 0; j < 4; ++j) {
      float4 f = *(const float4*)(sp + j * 4);
      tile[kl][nc + j * 4 + 0] = f2b(f.x);
      tile[kl][nc + j * 4 + 1] = f2b(f.y);
      tile[kl][nc + j * 4 + 2] = f2b(f.z);
      tile[kl][nc + j * 4 + 3] = f2b(f.w);
    }
  }
  __syncthreads();
  {
    const int nl = t >> 2, kc = (t & 3) * 16;
    u16x8 o0, o1;
#pragma unroll
    for (int j = 0; j < 8; ++j) { o0[j] = tile[kc + j][nl]; o1[j] = tile[kc + 8 + j][nl]; }
    u16* dp = dst + (size_t)(n0 + nl) * K + k0 + kc;
    *(u16x8*)dp = o0;
    *(u16x8*)(dp + 8) = o1;
  }
}

__global__ void bias_cat2(const float* __restrict__ a, const float* __restrict__ b,
                          float* __restrict__ o) {
  int i = blockIdx.x * 256 + threadIdx.x;
  if (i < 2048) o[i] = (i < 1024) ? a[i] : b[i - 1024];
}

// desc0|desc1 -> CAT left half bf16 (ld 2048)
__global__ void prep_x(const float* __restrict__ d0, const float* __restrict__ d1,
                       u16* __restrict__ CAT) {
  size_t i4 = ((size_t)blockIdx.x * 256 + threadIdx.x) * 4;
  const float* src = (i4 < 4194304) ? (d0 + i4) : (d1 + (i4 - 4194304));
  float4 v = *(const float4*)src;
  size_t row = i4 >> 10, col = i4 & 1023;
  u16x4 o = {f2b(v.x), f2b(v.y), f2b(v.z), f2b(v.w)};
  *(u16x4*)(CAT + row * 2048 + col) = o;
}

// ---------------------------------------------------------------------------
// GEMM: C[M][N] = A[M][K](bf16) @ W[K][N] + bias;  B given as W^T [N][K] bf16.
// 128x128 tile, BK=32, 4 waves (2x2), 16 MFMA 16x16x32 per wave per K-step.
// Epilogue: optional fp32 out, optional bf16 out (ldob/coloff), optional fp32
// residual with row-split across two source pointers.
// ---------------------------------------------------------------------------
template <int WF32, int WBF16, int RES>
__global__ __launch_bounds__(256) void gemm_bt(
    const u16* __restrict__ A, int lda, const u16* __restrict__ Bt, int ldb,
    const float* __restrict__ bias, int K, float* __restrict__ outf, int ldf,
    u16* __restrict__ outb, int ldob, int coloff, const float* __restrict__ res,
    const float* __restrict__ res2, int rsplit, int ldr) {
  __shared__ __align__(16) u16 As[128 * 32];
  __shared__ __align__(16) u16 Bs[128 * 32];
  const int m0 = blockIdx.y * 128, n0 = blockIdx.x * 128;
  const int t = threadIdx.x;
  const int w = t >> 6, l = t & 63;
  const int wr = (w >> 1) * 64, wc = (w & 1) * 64;
  const int lr = l & 15, lg = l >> 4;
  f32x4 acc[4][4] = {};
  const u16* Ab = A + (size_t)m0 * lda;
  const u16* Bb = Bt + (size_t)n0 * ldb;
  const int srow = t >> 2;
  const int scol = (t & 3) * 8;
  for (int k0 = 0; k0 < K; k0 += 32) {
    gload16(Ab + (size_t)srow * lda + k0 + scol, &As[srow * 32 + scol]);
    gload16(Ab + (size_t)(srow + 64) * lda + k0 + scol, &As[(srow + 64) * 32 + scol]);
    gload16(Bb + (size_t)srow * ldb + k0 + scol, &Bs[srow * 32 + scol]);
    gload16(Bb + (size_t)(srow + 64) * ldb + k0 + scol, &Bs[(srow + 64) * 32 + scol]);
    __syncthreads();
    bf16x8 af[4], bfr[4];
#pragma unroll
    for (int m = 0; m < 4; ++m) af[m] = *(const bf16x8*)&As[(wr + m * 16 + lr) * 32 + lg * 8];
#pragma unroll
    for (int n = 0; n < 4; ++n) bfr[n] = *(const bf16x8*)&Bs[(wc + n * 16 + lr) * 32 + lg * 8];
#pragma unroll
    for (int m = 0; m < 4; ++m)
#pragma unroll
      for (int n = 0; n < 4; ++n) acc[m][n] = MFMA16(af[m], bfr[n], acc[m][n]);
    __syncthreads();
  }
#pragma unroll
  for (int m = 0; m < 4; ++m) {
#pragma unroll
    for (int n = 0; n < 4; ++n) {
#pragma unroll
      for (int r = 0; r < 4; ++r) {
        const int row = m0 + wr + m * 16 + lg * 4 + r;
        const int col = n0 + wc + n * 16 + lr;
        float v = acc[m][n][r] + bias[col];
        if (RES) {
          const float* rp = res;
          int rr = row;
          if (row >= rsplit) { rp = res2; rr = row - rsplit; }
          v += rp[(size_t)rr * ldr + col];
        }
        if (WF32) outf[(size_t)row * ldf + col] = v;
        if (WBF16) outb[(size_t)row * ldob + coloff + col] = f2b(v);
      }
    }
  }
}

// ---------------------------------------------------------------------------
// QKV split + RoPE.  QKV bf16 [8192][3072], col = h*192 + d*3 + {0:q,1:k,2:v}.
// Writes q,k (roped) and v into [8192][1024] bf16 (col = h*64+d).
// ---------------------------------------------------------------------------
__global__ __launch_bounds__(256) void rope_split(
    const u16* __restrict__ QKV, const float* __restrict__ enc0,
    const float* __restrict__ enc1, u16* __restrict__ qo, u16* __restrict__ ko,
    u16* __restrict__ vo) {
  const int p = blockIdx.x, nt = blockIdx.y;
  const int bdb = p >> 4, h = p & 15;
  const int t = threadIdx.x;
  const int ip = t & 31, nl = t >> 5;
  const float* enc = (bdb < 2) ? enc0 : enc1;
  const float* e0base = enc + (size_t)(bdb & 1) * 131072 + ip * 2;  // [2,B,1,N,64]
#pragma unroll 4
  for (int it = 0; it < 16; ++it) {
    const int n = nt * 128 + it * 8 + nl;
    const size_t row = (size_t)bdb * 2048 + n;
    const unsigned* su = (const unsigned*)(QKV + row * 3072 + h * 192 + ip * 6);
    const unsigned u0 = su[0], u1 = su[1], u2 = su[2];
    const float qe = b2f((u16)u0), ke = b2f((u16)(u0 >> 16));
    const u16 vbe = (u16)u1;
    const float qot = b2f((u16)(u1 >> 16));
    const float kot = b2f((u16)u2);
    const u16 vbo = (u16)(u2 >> 16);
    const float* ep = e0base + (size_t)n * 64;
    const float2 f0 = *(const float2*)ep;
    const float2 f1 = *(const float2*)(ep + 262144);
    u16x2 qw = {f2b(qe * f0.x - qot * f1.x), f2b(qot * f0.y + qe * f1.y)};
    u16x2 kw = {f2b(ke * f0.x - kot * f1.x), f2b(kot * f0.y + ke * f1.y)};
    u16x2 vw = {vbe, vbo};
    const size_t ob = row * 1024 + h * 64 + ip * 2;
    *(u16x2*)(qo + ob) = qw;
    *(u16x2*)(ko + ob) = kw;
    *(u16x2*)(vo + ob) = vw;
  }
}

// per-head V transpose: in [8192][in_ld] bf16 (head cols at col_off+h*64) ->
// out [64 problems][64 d][2048 n]
__global__ __launch_bounds__(256) void vtrans(const u16* __restrict__ in, int in_ld,
                                              int col_off, u16* __restrict__ out) {
  const int p = blockIdx.x, nt = blockIdx.y;
  const int bdb = p >> 4, h = p & 15;
  const int t = threadIdx.x;
  __shared__ __align__(16) u16 tile[64][72];
  {
    const int nl = t >> 2, dc = (t & 3) * 16;
    const u16* sp = in + (size_t)(bdb * 2048 + nt * 64 + nl) * in_ld + col_off + h * 64 + dc;
    u16x8 a = *(const u16x8*)sp;
    u16x8 b = *(const u16x8*)(sp + 8);
#pragma unroll
    for (int j = 0; j < 8; ++j) { tile[nl][dc + j] = a[j]; tile[nl][dc + 8 + j] = b[j]; }
  }
  __syncthreads();
  {
    const int d = t >> 2, nc = (t & 3) * 16;
    u16x8 o0, o1;
#pragma unroll
    for (int j = 0; j < 8; ++j) { o0[j] = tile[nc + j][d]; o1[j] = tile[nc + 8 + j][d]; }
    u16* dp = out + (size_t)p * 131072 + (size_t)d * 2048 + nt * 64 + nc;
    *(u16x8*)dp = o0;
    *(u16x8*)(dp + 8) = o1;
  }
}

// ---------------------------------------------------------------------------
// Flash attention, HD=64, N=2048, scale=1/8.  4 waves x 16 q-rows, KT=64.
// mode 0: self (p = bdb*16+h);  mode 1: cross (K/V from the other descriptor)
// ---------------------------------------------------------------------------
__global__ __launch_bounds__(256) void attn_fa(const u16* __restrict__ qbase, int q_ld,
                                               const u16* __restrict__ kbase, int k_ld,
                                               const u16* __restrict__ vtbase,
                                               u16* __restrict__ ctxbase, int mode) {
  const int qb = blockIdx.x;  // 0..31
  const int p = blockIdx.y;   // 0..63
  const int t = threadIdx.x, w = t >> 6, l = t & 63;
  const int lr = l & 15, lg = l >> 4;

  const u16 *qp, *kp, *vtp;
  u16* op;
  if (mode == 0) {
    const int bdb = p >> 4, h = p & 15;
    const size_t rb = (size_t)bdb * 2048;
    qp = qbase + rb * q_ld + h * 64;
    kp = kbase + rb * k_ld + h * 64;
    vtp = vtbase + (size_t)p * 131072;
    op = ctxbase + rb * 1024 + h * 64;
  } else {
    const int bd = p >> 5, b = (p >> 4) & 1, h = p & 15;
    const size_t qrb = (size_t)bd * 4096 + (size_t)b * 2048;
    const size_t krb = (size_t)(1 - bd) * 4096 + (size_t)b * 2048;
    qp = qbase + qrb * q_ld + h * 64;
    kp = kbase + krb * k_ld + h * 64;
    const int pv = ((1 - bd) * 2 + b) * 16 + h;
    vtp = vtbase + (size_t)pv * 131072;
    op = ctxbase + qrb * 1024 + h * 64;
  }

  __shared__ __align__(16) u16 kbuf[64 * 64];
  __shared__ __align__(16) u16 vbuf[64 * 64];
  __shared__ __align__(16) u16 pbuf[4][1024];

  const int qrow0 = qb * 64 + w * 16;
  const bf16x8 qa0 = *(const bf16x8*)(qp + (size_t)(qrow0 + lr) * q_ld + lg * 8);
  const bf16x8 qa1 = *(const bf16x8*)(qp + (size_t)(qrow0 + lr) * q_ld + 32 + lg * 8);

  f32x4 accO[4] = {};
  float mrun[4], lrun[4];
#pragma unroll
  for (int r = 0; r < 4; ++r) { mrun[r] = -1e30f; lrun[r] = 0.f; }

  const int sr0 = t >> 3, se0 = (t & 7) * 8;
  for (int kt = 0; kt < 2048; kt += 64) {
    gload16(kp + (size_t)(kt + sr0) * k_ld + se0, &kbuf[sr0 * 64 + se0]);
    gload16(kp + (size_t)(kt + sr0 + 32) * k_ld + se0, &kbuf[(sr0 + 32) * 64 + se0]);
    gload16(vtp + (size_t)sr0 * 2048 + kt + se0, &vbuf[sr0 * 64 + se0]);
    gload16(vtp + (size_t)(sr0 + 32) * 2048 + kt + se0, &vbuf[(sr0 + 32) * 64 + se0]);
    __syncthreads();

    // S = scale * Q K^T
    f32x4 s[4];
#pragma unroll
    for (int f = 0; f < 4; ++f) {
      const bf16x8 b0 = *(const bf16x8*)&kbuf[(f * 16 + lr) * 64 + lg * 8];
      const bf16x8 b1 = *(const bf16x8*)&kbuf[(f * 16 + lr) * 64 + 32 + lg * 8];
      f32x4 z = {};
      z = MFMA16(qa0, b0, z);
      z = MFMA16(qa1, b1, z);
      s[f] = z * 0.125f;
    }
    // online softmax
#pragma unroll
    for (int r = 0; r < 4; ++r) {
      float mt = fmaxf(fmaxf(s[0][r], s[1][r]), fmaxf(s[2][r], s[3][r]));
      mt = fmaxf(mt, __shfl_xor(mt, 1));
      mt = fmaxf(mt, __shfl_xor(mt, 2));
      mt = fmaxf(mt, __shfl_xor(mt, 4));
      mt = fmaxf(mt, __shfl_xor(mt, 8));
      const float mnew = fmaxf(mrun[r], mt);
      const float al = __expf(mrun[r] - mnew);
      mrun[r] = mnew;
      float pv0 = __expf(s[0][r] - mnew);
      float pv1 = __expf(s[1][r] - mnew);
      float pv2 = __expf(s[2][r] - mnew);
      float pv3 = __expf(s[3][r] - mnew);
      float rs = pv0 + pv1 + pv2 + pv3;
      rs += __shfl_xor(rs, 1);
      rs += __shfl_xor(rs, 2);
      rs += __shfl_xor(rs, 4);
      rs += __shfl_xor(rs, 8);
      lrun[r] = lrun[r] * al + rs;
#pragma unroll
      for (int nf = 0; nf < 4; ++nf) accO[nf][r] *= al;
      const int q = lg * 4 + r;
      pbuf[w][q * 64 + 0 * 16 + lr] = f2b(pv0);
      pbuf[w][q * 64 + 1 * 16 + lr] = f2b(pv1);
      pbuf[w][q * 64 + 2 * 16 + lr] = f2b(pv2);
      pbuf[w][q * 64 + 3 * 16 + lr] = f2b(pv3);
    }
    // O += P @ V
    const bf16x8 pa0 = *(const bf16x8*)&pbuf[w][lr * 64 + lg * 8];
    const bf16x8 pa1 = *(const bf16x8*)&pbuf[w][lr * 64 + 32 + lg * 8];
#pragma unroll
    for (int nf = 0; nf < 4; ++nf) {
      const bf16x8 v0 = *(const bf16x8*)&vbuf[(nf * 16 + lr) * 64 + lg * 8];
      const bf16x8 v1 = *(const bf16x8*)&vbuf[(nf * 16 + lr) * 64 + 32 + lg * 8];
      accO[nf] = MFMA16(pa0, v0, accO[nf]);
      accO[nf] = MFMA16(pa1, v1, accO[nf]);
    }
    __syncthreads();
  }
#pragma unroll
  for (int r = 0; r < 4; ++r) {
    const float inv = 1.f / lrun[r];
    const int row = qrow0 + lg * 4 + r;
#pragma unroll
    for (int nf = 0; nf < 4; ++nf)
      op[(size_t)row * 1024 + nf * 16 + lr] = f2b(accO[nf][r] * inv);
  }
}

// ---------------------------------------------------------------------------
// LayerNorm (over 2048) + exact GELU, bf16 in -> bf16 out (stats in fp32)
// ---------------------------------------------------------------------------
__global__ __launch_bounds__(256) void ln_gelu(const u16* __restrict__ H,
                                               const float* __restrict__ gam,
                                               const float* __restrict__ bet,
                                               u16* __restrict__ G) {
  const int row = blockIdx.x, t = threadIdx.x;
  u16x8 hv = *(const u16x8*)(H + (size_t)row * 2048 + t * 8);
  float v[8];
#pragma unroll
  for (int j = 0; j < 8; ++j) v[j] = b2f(hv[j]);
  float s = 0.f, s2 = 0.f;
#pragma unroll
  for (int j = 0; j < 8; ++j) { s += v[j]; s2 += v[j] * v[j]; }
#pragma unroll
  for (int off = 32; off; off >>= 1) { s += __shfl_xor(s, off); s2 += __shfl_xor(s2, off); }
  __shared__ float red[8];
  const int w = t >> 6, l = t & 63;
  if (l == 0) { red[w] = s; red[4 + w] = s2; }
  __syncthreads();
  s = red[0] + red[1] + red[2] + red[3];
  s2 = red[4] + red[5] + red[6] + red[7];
  const float mean = s * (1.f / 2048.f);
  const float rstd = rsqrtf(s2 * (1.f / 2048.f) - mean * mean + 1e-5f);
  u16x8 o;
#pragma unroll
  for (int j = 0; j < 8; ++j) {
    const int col = t * 8 + j;
    const float x = (v[j] - mean) * rstd * gam[col] + bet[col];
    o[j] = f2b(x * 0.5f * (1.f + erff(x * 0.7071067811865475f)));
  }
  *(u16x8*)(G + (size_t)row * 2048 + t * 8) = o;
}

// ---------------------------------------------------------------------------
extern "C" void kernel_launch(void* const* d_in, const int* in_sizes, int n_in,
                              void* d_out, int out_size, void* d_ws, size_t ws_size,
                              hipStream_t stream) {
  (void)in_sizes; (void)n_in; (void)out_size; (void)ws_size;
  const float* desc0 = (const float*)d_in[0];
  const float* desc1 = (const float*)d_in[1];
  const float* enc0 = (const float*)d_in[2];
  const float* enc1 = (const float*)d_in[3];
  const float* wqkv_w = (const float*)d_in[4];
  const float* wqkv_b = (const float*)d_in[5];
  const float* sout_w = (const float*)d_in[6];
  const float* sout_b = (const float*)d_in[7];
  const float* sf1_w = (const float*)d_in[8];
  const float* sf1_b = (const float*)d_in[9];
  const float* sln_g = (const float*)d_in[10];
  const float* sln_b = (const float*)d_in[11];
  const float* sf2_w = (const float*)d_in[12];
  const float* sf2_b = (const float*)d_in[13];
  const float* qk_w = (const float*)d_in[14];
  const float* qk_b = (const float*)d_in[15];
  const float* v_w = (const float*)d_in[16];
  const float* v_b = (const float*)d_in[17];
  const float* cout_w = (const float*)d_in[18];
  const float* cout_b = (const float*)d_in[19];
  const float* cf1_w = (const float*)d_in[20];
  const float* cf1_b = (const float*)d_in[21];
  const float* cln_g = (const float*)d_in[22];
  const float* cln_b = (const float*)d_in[23];
  const float* cf2_w = (const float*)d_in[24];
  const float* cf2_b = (const float*)d_in[25];

  char* ws = (char*)d_ws;
  size_t off = 0;
  auto alloc = [&](size_t n) { char* r = ws + off; off += (n + 255) & ~(size_t)255; return r; };
  // weights (bf16, transposed) — 38 MiB
  u16* wqkv_t = (u16*)alloc((size_t)3072 * 1024 * 2);
  u16* sout_t = (u16*)alloc((size_t)1024 * 1024 * 2);
  u16* sf1_t = (u16*)alloc((size_t)2048 * 2048 * 2);
  u16* sf2_t = (u16*)alloc((size_t)1024 * 2048 * 2);
  u16* wcat_t = (u16*)alloc((size_t)2048 * 1024 * 2);
  u16* cout_t = (u16*)alloc((size_t)1024 * 1024 * 2);
  u16* cf1_t = (u16*)alloc((size_t)2048 * 2048 * 2);
  u16* cf2_t = (u16*)alloc((size_t)1024 * 2048 * 2);
  float* biascat = (float*)alloc(2048 * 4);
  // activations
  u16* CATb = (u16*)alloc((size_t)8192 * 2048 * 2);     // 32 MiB  [x | msg]
  char* BIG = alloc((size_t)8192 * 3072 * 2);           // 48 MiB  QKVbf / Hbf / CQKV
  char* QKB = alloc((size_t)3 * 8192 * 1024 * 2);       // 48 MiB  q,k,v ; G over q+k; CTX over v
  u16* VT = (u16*)alloc((size_t)64 * 64 * 2048 * 2);    // 16 MiB
  // total ~182 MiB

  u16* QKVbf = (u16*)BIG;
  u16* Hbf = (u16*)BIG;
  u16* CQKV = (u16*)BIG;
  u16* qB = (u16*)QKB;
  u16* kB = qB + (size_t)8192 * 1024;
  u16* vB = kB + (size_t)8192 * 1024;
  u16* G = (u16*)QKB;             // overlays qB+kB (dead after attention)
  u16* CTX = vB;                  // overlays vB (dead after vtrans)
  float* OUT = (float*)d_out;     // fp32 [8192][1024]; self-Y stored here, then
                                  // final gemm reads it as residual in-place

  hipStream_t st = stream;
  // weight prep
  wtrans<<<dim3(48, 16), 256, 0, st>>>(wqkv_w, wqkv_t, 1024, 3072);
  wtrans<<<dim3(16, 16), 256, 0, st>>>(sout_w, sout_t, 1024, 1024);
  wtrans<<<dim3(32, 32), 256, 0, st>>>(sf1_w, sf1_t, 2048, 2048);
  wtrans<<<dim3(16, 32), 256, 0, st>>>(sf2_w, sf2_t, 2048, 1024);
  wtrans<<<dim3(16, 16), 256, 0, st>>>(qk_w, wcat_t, 1024, 1024);
  wtrans<<<dim3(16, 16), 256, 0, st>>>(v_w, wcat_t + (size_t)1024 * 1024, 1024, 1024);
  wtrans<<<dim3(16, 16), 256, 0, st>>>(cout_w, cout_t, 1024, 1024);
  wtrans<<<dim3(32, 32), 256, 0, st>>>(cf1_w, cf1_t, 2048, 2048);
  wtrans<<<dim3(16, 32), 256, 0, st>>>(cf2_w, cf2_t, 2048, 1024);
  bias_cat2<<<8, 256, 0, st>>>(qk_b, v_b, biascat);
  prep_x<<<8192, 256, 0, st>>>(desc0, desc1, CATb);

  // ---- self blocks (batched desc0+desc1) ----
  gemm_bt<0, 1, 0><<<dim3(24, 64), 256, 0, st>>>(CATb, 2048, wqkv_t, 1024, wqkv_b, 1024,
                                                 nullptr, 0, QKVbf, 3072, 0, nullptr,
                                                 nullptr, 1 << 30, 0);
  rope_split<<<dim3(64, 16), 256, 0, st>>>(QKVbf, enc0, enc1, qB, kB, vB);
  vtrans<<<dim3(64, 32), 256, 0, st>>>(vB, 1024, 0, VT);
  attn_fa<<<dim3(32, 64), 256, 0, st>>>(qB, 1024, kB, 1024, VT, CTX, 0);
  gemm_bt<0, 1, 0><<<dim3(8, 64), 256, 0, st>>>(CTX, 1024, sout_t, 1024, sout_b, 1024,
                                                nullptr, 0, CATb, 2048, 1024, nullptr,
                                                nullptr, 1 << 30, 0);
  gemm_bt<0, 1, 0><<<dim3(16, 64), 256, 0, st>>>(CATb, 2048, sf1_t, 2048, sf1_b, 2048,
                                                 nullptr, 0, Hbf, 2048, 0, nullptr,
                                                 nullptr, 1 << 30, 0);
  ln_gelu<<<8192, 256, 0, st>>>(Hbf, sln_g, sln_b, G);
  gemm_bt<1, 1, 1><<<dim3(8, 64), 256, 0, st>>>(G, 2048, sf2_t, 2048, sf2_b, 2048,
                                                OUT, 1024, CATb, 2048, 0, desc0,
                                                desc1, 4096, 1024);

  // ---- cross block ----
  gemm_bt<0, 1, 0><<<dim3(16, 64), 256, 0, st>>>(CATb, 2048, wcat_t, 1024, biascat, 1024,
                                                 nullptr, 0, CQKV, 2048, 0, nullptr,
                                                 nullptr, 1 << 30, 0);
  vtrans<<<dim3(64, 32), 256, 0, st>>>(CQKV, 2048, 1024, VT);
  attn_fa<<<dim3(32, 64), 256, 0, st>>>(CQKV, 2048, CQKV, 2048, VT, CTX, 1);
  gemm_bt<0, 1, 0><<<dim3(8, 64), 256, 0, st>>>(CTX, 1024, cout_t, 1024, cout_b, 1024,
                                                nullptr, 0, CATb, 2048, 1024, nullptr,
                                                nullptr, 1 << 30, 0);
  gemm_bt<0, 1, 0><<<dim3(16, 64), 256, 0, st>>>(CATb, 2048, cf1_t, 2048, cf1_b, 2048,
                                                 nullptr, 0, Hbf, 2048, 0, nullptr,
                                                 nullptr, 1 << 30, 0);
  ln_gelu<<<8192, 256, 0, st>>>(Hbf, cln_g, cln_b, G);
  gemm_bt<1, 0, 1><<<dim3(8, 64), 256, 0, st>>>(G, 2048, cf2_t, 2048, cf2_b, 2048,
                                                OUT, 1024, nullptr, 0, 0, OUT,
                                                OUT, 1 << 30, 1024);
}

// Round 3
// 1369.998 us; speedup vs baseline: 1.0724x; 1.0724x over previous
//
#include <hip/hip_runtime.h>

// TransformerLayer on MI355X: 2x self-block (shared weights, batched) + cross-block.
// All activations bf16 for MFMA GEMMs, fp32 accumulate, fp32 residual path.
// B=2, N=2048, D=1024, H=16, HD=64 -> M = 2*B*N = 8192 rows everywhere.
// R2 -> R3: attn_fa gets (1) LDS XOR-swizzle via pre-swizzled global source,
// (2) double-buffered K/V with stage-before-compute, (3) setprio around MFMA.

typedef unsigned short u16;
typedef float f32x4 __attribute__((ext_vector_type(4)));
typedef __bf16 bf16x8 __attribute__((ext_vector_type(8)));
typedef u16 u16x2 __attribute__((ext_vector_type(2)));
typedef u16 u16x4 __attribute__((ext_vector_type(4)));
typedef u16 u16x8 __attribute__((ext_vector_type(8)));

__device__ __forceinline__ u16 f2b(float f) {
  union { float f; unsigned u; } v; v.f = f;
  unsigned r = v.u + 0x7FFFu + ((v.u >> 16) & 1u);  // RNE
  return (u16)(r >> 16);
}
__device__ __forceinline__ float b2f(u16 s) {
  union { unsigned u; float f; } v; v.u = ((unsigned)s) << 16;
  return v.f;
}
__device__ __forceinline__ void gload16(const void* g, void* l) {
  __builtin_amdgcn_global_load_lds((const __attribute__((address_space(1))) void*)g,
                                   (__attribute__((address_space(3))) void*)l, 16, 0, 0);
}
#define MFMA16(a, b, c) __builtin_amdgcn_mfma_f32_16x16x32_bf16(a, b, c, 0, 0, 0)

// ---------------------------------------------------------------------------
// Weight prep: fp32 [K][N] -> bf16 [N][K] (B^T layout for the GEMM)
// ---------------------------------------------------------------------------
__global__ __launch_bounds__(256) void wtrans(const float* __restrict__ src,
                                              u16* __restrict__ dst, int K, int N) {
  __shared__ __align__(16) u16 tile[64][72];
  const int k0 = blockIdx.y * 64, n0 = blockIdx.x * 64;
  const int t = threadIdx.x;
  {
    const int kl = t >> 2, nc = (t & 3) * 16;
    const float* sp = src + (size_t)(k0 + kl) * N + n0 + nc;
#pragma unroll
    for (int j = 0; j < 4; ++j) {
      float4 f = *(const float4*)(sp + j * 4);
      tile[kl][nc + j * 4 + 0] = f2b(f.x);
      tile[kl][nc + j * 4 + 1] = f2b(f.y);
      tile[kl][nc + j * 4 + 2] = f2b(f.z);
      tile[kl][nc + j * 4 + 3] = f2b(f.w);
    }
  }
  __syncthreads();
  {
    const int nl = t >> 2, kc = (t & 3) * 16;
    u16x8 o0, o1;
#pragma unroll
    for (int j = 0; j < 8; ++j) { o0[j] = tile[kc + j][nl]; o1[j] = tile[kc + 8 + j][nl]; }
    u16* dp = dst + (size_t)(n0 + nl) * K + k0 + kc;
    *(u16x8*)dp = o0;
    *(u16x8*)(dp + 8) = o1;
  }
}

__global__ void bias_cat2(const float* __restrict__ a, const float* __restrict__ b,
                          float* __restrict__ o) {
  int i = blockIdx.x * 256 + threadIdx.x;
  if (i < 2048) o[i] = (i < 1024) ? a[i] : b[i - 1024];
}

// desc0|desc1 -> CAT left half bf16 (ld 2048)
__global__ void prep_x(const float* __restrict__ d0, const float* __restrict__ d1,
                       u16* __restrict__ CAT) {
  size_t i4 = ((size_t)blockIdx.x * 256 + threadIdx.x) * 4;
  const float* src = (i4 < 4194304) ? (d0 + i4) : (d1 + (i4 - 4194304));
  float4 v = *(const float4*)src;
  size_t row = i4 >> 10, col = i4 & 1023;
  u16x4 o = {f2b(v.x), f2b(v.y), f2b(v.z), f2b(v.w)};
  *(u16x4*)(CAT + row * 2048 + col) = o;
}

// ---------------------------------------------------------------------------
// GEMM: C[M][N] = A[M][K](bf16) @ W[K][N] + bias;  B given as W^T [N][K] bf16.
// 128x128 tile, BK=32, 4 waves (2x2), 16 MFMA 16x16x32 per wave per K-step.
// ---------------------------------------------------------------------------
template <int WF32, int WBF16, int RES>
__global__ __launch_bounds__(256) void gemm_bt(
    const u16* __restrict__ A, int lda, const u16* __restrict__ Bt, int ldb,
    const float* __restrict__ bias, int K, float* __restrict__ outf, int ldf,
    u16* __restrict__ outb, int ldob, int coloff, const float* __restrict__ res,
    const float* __restrict__ res2, int rsplit, int ldr) {
  __shared__ __align__(16) u16 As[128 * 32];
  __shared__ __align__(16) u16 Bs[128 * 32];
  const int m0 = blockIdx.y * 128, n0 = blockIdx.x * 128;
  const int t = threadIdx.x;
  const int w = t >> 6, l = t & 63;
  const int wr = (w >> 1) * 64, wc = (w & 1) * 64;
  const int lr = l & 15, lg = l >> 4;
  f32x4 acc[4][4] = {};
  const u16* Ab = A + (size_t)m0 * lda;
  const u16* Bb = Bt + (size_t)n0 * ldb;
  const int srow = t >> 2;
  const int scol = (t & 3) * 8;
  for (int k0 = 0; k0 < K; k0 += 32) {
    gload16(Ab + (size_t)srow * lda + k0 + scol, &As[srow * 32 + scol]);
    gload16(Ab + (size_t)(srow + 64) * lda + k0 + scol, &As[(srow + 64) * 32 + scol]);
    gload16(Bb + (size_t)srow * ldb + k0 + scol, &Bs[srow * 32 + scol]);
    gload16(Bb + (size_t)(srow + 64) * ldb + k0 + scol, &Bs[(srow + 64) * 32 + scol]);
    __syncthreads();
    bf16x8 af[4], bfr[4];
#pragma unroll
    for (int m = 0; m < 4; ++m) af[m] = *(const bf16x8*)&As[(wr + m * 16 + lr) * 32 + lg * 8];
#pragma unroll
    for (int n = 0; n < 4; ++n) bfr[n] = *(const bf16x8*)&Bs[(wc + n * 16 + lr) * 32 + lg * 8];
#pragma unroll
    for (int m = 0; m < 4; ++m)
#pragma unroll
      for (int n = 0; n < 4; ++n) acc[m][n] = MFMA16(af[m], bfr[n], acc[m][n]);
    __syncthreads();
  }
#pragma unroll
  for (int m = 0; m < 4; ++m) {
#pragma unroll
    for (int n = 0; n < 4; ++n) {
#pragma unroll
      for (int r = 0; r < 4; ++r) {
        const int row = m0 + wr + m * 16 + lg * 4 + r;
        const int col = n0 + wc + n * 16 + lr;
        float v = acc[m][n][r] + bias[col];
        if (RES) {
          const float* rp = res;
          int rr = row;
          if (row >= rsplit) { rp = res2; rr = row - rsplit; }
          v += rp[(size_t)rr * ldr + col];
        }
        if (WF32) outf[(size_t)row * ldf + col] = v;
        if (WBF16) outb[(size_t)row * ldob + coloff + col] = f2b(v);
      }
    }
  }
}

// ---------------------------------------------------------------------------
// QKV split + RoPE.  QKV bf16 [8192][3072], col = h*192 + d*3 + {0:q,1:k,2:v}.
// ---------------------------------------------------------------------------
__global__ __launch_bounds__(256) void rope_split(
    const u16* __restrict__ QKV, const float* __restrict__ enc0,
    const float* __restrict__ enc1, u16* __restrict__ qo, u16* __restrict__ ko,
    u16* __restrict__ vo) {
  const int p = blockIdx.x, nt = blockIdx.y;
  const int bdb = p >> 4, h = p & 15;
  const int t = threadIdx.x;
  const int ip = t & 31, nl = t >> 5;
  const float* enc = (bdb < 2) ? enc0 : enc1;
  const float* e0base = enc + (size_t)(bdb & 1) * 131072 + ip * 2;  // [2,B,1,N,64]
#pragma unroll 4
  for (int it = 0; it < 16; ++it) {
    const int n = nt * 128 + it * 8 + nl;
    const size_t row = (size_t)bdb * 2048 + n;
    const unsigned* su = (const unsigned*)(QKV + row * 3072 + h * 192 + ip * 6);
    const unsigned u0 = su[0], u1 = su[1], u2 = su[2];
    const float qe = b2f((u16)u0), ke = b2f((u16)(u0 >> 16));
    const u16 vbe = (u16)u1;
    const float qot = b2f((u16)(u1 >> 16));
    const float kot = b2f((u16)u2);
    const u16 vbo = (u16)(u2 >> 16);
    const float* ep = e0base + (size_t)n * 64;
    const float2 f0 = *(const float2*)ep;
    const float2 f1 = *(const float2*)(ep + 262144);
    u16x2 qw = {f2b(qe * f0.x - qot * f1.x), f2b(qot * f0.y + qe * f1.y)};
    u16x2 kw = {f2b(ke * f0.x - kot * f1.x), f2b(kot * f0.y + ke * f1.y)};
    u16x2 vw = {vbe, vbo};
    const size_t ob = row * 1024 + h * 64 + ip * 2;
    *(u16x2*)(qo + ob) = qw;
    *(u16x2*)(ko + ob) = kw;
    *(u16x2*)(vo + ob) = vw;
  }
}

// per-head V transpose: in [8192][in_ld] bf16 -> out [64 problems][64 d][2048 n]
__global__ __launch_bounds__(256) void vtrans(const u16* __restrict__ in, int in_ld,
                                              int col_off, u16* __restrict__ out) {
  const int p = blockIdx.x, nt = blockIdx.y;
  const int bdb = p >> 4, h = p & 15;
  const int t = threadIdx.x;
  __shared__ __align__(16) u16 tile[64][72];
  {
    const int nl = t >> 2, dc = (t & 3) * 16;
    const u16* sp = in + (size_t)(bdb * 2048 + nt * 64 + nl) * in_ld + col_off + h * 64 + dc;
    u16x8 a = *(const u16x8*)sp;
    u16x8 b = *(const u16x8*)(sp + 8);
#pragma unroll
    for (int j = 0; j < 8; ++j) { tile[nl][dc + j] = a[j]; tile[nl][dc + 8 + j] = b[j]; }
  }
  __syncthreads();
  {
    const int d = t >> 2, nc = (t & 3) * 16;
    u16x8 o0, o1;
#pragma unroll
    for (int j = 0; j < 8; ++j) { o0[j] = tile[nc + j][d]; o1[j] = tile[nc + 8 + j][d]; }
    u16* dp = out + (size_t)p * 131072 + (size_t)d * 2048 + nt * 64 + nc;
    *(u16x8*)dp = o0;
    *(u16x8*)(dp + 8) = o1;
  }
}

// ---------------------------------------------------------------------------
// Flash attention, HD=64, N=2048, scale=1/8.  4 waves x 16 q-rows, KT=64.
// K/V double-buffered in LDS; XOR-swizzled layout (global source pre-swizzled,
// reads XOR (row&7)<<3 in u16 units).  mode 0: self;  mode 1: cross.
// ---------------------------------------------------------------------------
__global__ __launch_bounds__(256) void attn_fa(const u16* __restrict__ qbase, int q_ld,
                                               const u16* __restrict__ kbase, int k_ld,
                                               const u16* __restrict__ vtbase,
                                               u16* __restrict__ ctxbase, int mode) {
  const int qb = blockIdx.x;  // 0..31
  const int p = blockIdx.y;   // 0..63
  const int t = threadIdx.x, w = t >> 6, l = t & 63;
  const int lr = l & 15, lg = l >> 4;

  const u16 *qp, *kp, *vtp;
  u16* op;
  if (mode == 0) {
    const int bdb = p >> 4, h = p & 15;
    const size_t rb = (size_t)bdb * 2048;
    qp = qbase + rb * q_ld + h * 64;
    kp = kbase + rb * k_ld + h * 64;
    vtp = vtbase + (size_t)p * 131072;
    op = ctxbase + rb * 1024 + h * 64;
  } else {
    const int bd = p >> 5, b = (p >> 4) & 1, h = p & 15;
    const size_t qrb = (size_t)bd * 4096 + (size_t)b * 2048;
    const size_t krb = (size_t)(1 - bd) * 4096 + (size_t)b * 2048;
    qp = qbase + qrb * q_ld + h * 64;
    kp = kbase + krb * k_ld + h * 64;
    const int pv = ((1 - bd) * 2 + b) * 16 + h;
    vtp = vtbase + (size_t)pv * 131072;
    op = ctxbase + qrb * 1024 + h * 64;
  }

  __shared__ __align__(16) u16 kbuf[2][64 * 64];
  __shared__ __align__(16) u16 vbuf[2][64 * 64];
  __shared__ __align__(16) u16 pbuf[4][1024];

  const int qrow0 = qb * 64 + w * 16;
  const bf16x8 qa0 = *(const bf16x8*)(qp + (size_t)(qrow0 + lr) * q_ld + lg * 8);
  const bf16x8 qa1 = *(const bf16x8*)(qp + (size_t)(qrow0 + lr) * q_ld + 32 + lg * 8);

  f32x4 accO[4] = {};
  float mrun[4], lrun[4];
#pragma unroll
  for (int r = 0; r < 4; ++r) { mrun[r] = -1e30f; lrun[r] = 0.f; }

  // staging geometry: thread t -> LDS row sr0 = t>>3 (linear dest), global col
  // group pre-swizzled so that LDS(row, c8) holds global (row, c8 ^ (row&7)).
  const int sr0 = t >> 3;
  const int sc8 = ((t & 7) ^ (sr0 & 7)) * 8;        // swizzled source col (u16)
  const int ldst = sr0 * 64 + (t & 7) * 8;          // linear LDS dest (u16)
  const int swz = (lr & 7) << 3;                    // read-side XOR (u16 units)

  // prologue: stage tile 0 into buffer 0
  gload16(kp + (size_t)sr0 * k_ld + sc8, &kbuf[0][ldst]);
  gload16(kp + (size_t)(sr0 + 32) * k_ld + sc8, &kbuf[0][ldst + 2048]);
  gload16(vtp + (size_t)sr0 * 2048 + sc8, &vbuf[0][ldst]);
  gload16(vtp + (size_t)(sr0 + 32) * 2048 + sc8, &vbuf[0][ldst + 2048]);
  __syncthreads();

  for (int it = 0; it < 32; ++it) {
    const int cur = it & 1;
    if (it < 31) {  // stage next tile into the other buffer (overlaps compute)
      const int kt = (it + 1) * 64;
      u16* kd = &kbuf[cur ^ 1][ldst];
      u16* vd = &vbuf[cur ^ 1][ldst];
      gload16(kp + (size_t)(kt + sr0) * k_ld + sc8, kd);
      gload16(kp + (size_t)(kt + sr0 + 32) * k_ld + sc8, kd + 2048);
      gload16(vtp + (size_t)sr0 * 2048 + kt + sc8, vd);
      gload16(vtp + (size_t)(sr0 + 32) * 2048 + kt + sc8, vd + 2048);
    }
    const u16* kb = kbuf[cur];
    const u16* vb = vbuf[cur];

    // S = scale * Q K^T
    f32x4 s[4];
    __builtin_amdgcn_s_setprio(1);
#pragma unroll
    for (int f = 0; f < 4; ++f) {
      const bf16x8 b0 = *(const bf16x8*)&kb[(f * 16 + lr) * 64 + ((lg * 8) ^ swz)];
      const bf16x8 b1 = *(const bf16x8*)&kb[(f * 16 + lr) * 64 + (((lg + 4) * 8) ^ swz)];
      f32x4 z = {};
      z = MFMA16(qa0, b0, z);
      z = MFMA16(qa1, b1, z);
      s[f] = z * 0.125f;
    }
    __builtin_amdgcn_s_setprio(0);

    // online softmax
#pragma unroll
    for (int r = 0; r < 4; ++r) {
      float mt = fmaxf(fmaxf(s[0][r], s[1][r]), fmaxf(s[2][r], s[3][r]));
      mt = fmaxf(mt, __shfl_xor(mt, 1));
      mt = fmaxf(mt, __shfl_xor(mt, 2));
      mt = fmaxf(mt, __shfl_xor(mt, 4));
      mt = fmaxf(mt, __shfl_xor(mt, 8));
      const float mnew = fmaxf(mrun[r], mt);
      const float al = __expf(mrun[r] - mnew);
      mrun[r] = mnew;
      float pv0 = __expf(s[0][r] - mnew);
      float pv1 = __expf(s[1][r] - mnew);
      float pv2 = __expf(s[2][r] - mnew);
      float pv3 = __expf(s[3][r] - mnew);
      float rs = pv0 + pv1 + pv2 + pv3;
      rs += __shfl_xor(rs, 1);
      rs += __shfl_xor(rs, 2);
      rs += __shfl_xor(rs, 4);
      rs += __shfl_xor(rs, 8);
      lrun[r] = lrun[r] * al + rs;
#pragma unroll
      for (int nf = 0; nf < 4; ++nf) accO[nf][r] *= al;
      const int q = lg * 4 + r;
      const int qs = (q & 7) << 3;
      pbuf[w][q * 64 + ((0 * 16 + lr) ^ qs)] = f2b(pv0);
      pbuf[w][q * 64 + ((1 * 16 + lr) ^ qs)] = f2b(pv1);
      pbuf[w][q * 64 + ((2 * 16 + lr) ^ qs)] = f2b(pv2);
      pbuf[w][q * 64 + ((3 * 16 + lr) ^ qs)] = f2b(pv3);
    }

    // O += P @ V
    const bf16x8 pa0 = *(const bf16x8*)&pbuf[w][lr * 64 + ((lg * 8) ^ swz)];
    const bf16x8 pa1 = *(const bf16x8*)&pbuf[w][lr * 64 + (((lg + 4) * 8) ^ swz)];
    __builtin_amdgcn_s_setprio(1);
#pragma unroll
    for (int nf = 0; nf < 4; ++nf) {
      const bf16x8 v0 = *(const bf16x8*)&vb[(nf * 16 + lr) * 64 + ((lg * 8) ^ swz)];
      const bf16x8 v1 = *(const bf16x8*)&vb[(nf * 16 + lr) * 64 + (((lg + 4) * 8) ^ swz)];
      accO[nf] = MFMA16(pa0, v0, accO[nf]);
      accO[nf] = MFMA16(pa1, v1, accO[nf]);
    }
    __builtin_amdgcn_s_setprio(0);
    __syncthreads();  // drains vmcnt (next-tile stage) + syncs buffers
  }
#pragma unroll
  for (int r = 0; r < 4; ++r) {
    const float inv = 1.f / lrun[r];
    const int row = qrow0 + lg * 4 + r;
#pragma unroll
    for (int nf = 0; nf < 4; ++nf)
      op[(size_t)row * 1024 + nf * 16 + lr] = f2b(accO[nf][r] * inv);
  }
}

// ---------------------------------------------------------------------------
// LayerNorm (over 2048) + exact GELU, bf16 in -> bf16 out (stats in fp32)
// ---------------------------------------------------------------------------
__global__ __launch_bounds__(256) void ln_gelu(const u16* __restrict__ H,
                                               const float* __restrict__ gam,
                                               const float* __restrict__ bet,
                                               u16* __restrict__ G) {
  const int row = blockIdx.x, t = threadIdx.x;
  u16x8 hv = *(const u16x8*)(H + (size_t)row * 2048 + t * 8);
  float v[8];
#pragma unroll
  for (int j = 0; j < 8; ++j) v[j] = b2f(hv[j]);
  float s = 0.f, s2 = 0.f;
#pragma unroll
  for (int j = 0; j < 8; ++j) { s += v[j]; s2 += v[j] * v[j]; }
#pragma unroll
  for (int off = 32; off; off >>= 1) { s += __shfl_xor(s, off); s2 += __shfl_xor(s2, off); }
  __shared__ float red[8];
  const int w = t >> 6, l = t & 63;
  if (l == 0) { red[w] = s; red[4 + w] = s2; }
  __syncthreads();
  s = red[0] + red[1] + red[2] + red[3];
  s2 = red[4] + red[5] + red[6] + red[7];
  const float mean = s * (1.f / 2048.f);
  const float rstd = rsqrtf(s2 * (1.f / 2048.f) - mean * mean + 1e-5f);
  u16x8 o;
#pragma unroll
  for (int j = 0; j < 8; ++j) {
    const int col = t * 8 + j;
    const float x = (v[j] - mean) * rstd * gam[col] + bet[col];
    o[j] = f2b(x * 0.5f * (1.f + erff(x * 0.7071067811865475f)));
  }
  *(u16x8*)(G + (size_t)row * 2048 + t * 8) = o;
}

// ---------------------------------------------------------------------------
extern "C" void kernel_launch(void* const* d_in, const int* in_sizes, int n_in,
                              void* d_out, int out_size, void* d_ws, size_t ws_size,
                              hipStream_t stream) {
  (void)in_sizes; (void)n_in; (void)out_size; (void)ws_size;
  const float* desc0 = (const float*)d_in[0];
  const float* desc1 = (const float*)d_in[1];
  const float* enc0 = (const float*)d_in[2];
  const float* enc1 = (const float*)d_in[3];
  const float* wqkv_w = (const float*)d_in[4];
  const float* wqkv_b = (const float*)d_in[5];
  const float* sout_w = (const float*)d_in[6];
  const float* sout_b = (const float*)d_in[7];
  const float* sf1_w = (const float*)d_in[8];
  const float* sf1_b = (const float*)d_in[9];
  const float* sln_g = (const float*)d_in[10];
  const float* sln_b = (const float*)d_in[11];
  const float* sf2_w = (const float*)d_in[12];
  const float* sf2_b = (const float*)d_in[13];
  const float* qk_w = (const float*)d_in[14];
  const float* qk_b = (const float*)d_in[15];
  const float* v_w = (const float*)d_in[16];
  const float* v_b = (const float*)d_in[17];
  const float* cout_w = (const float*)d_in[18];
  const float* cout_b = (const float*)d_in[19];
  const float* cf1_w = (const float*)d_in[20];
  const float* cf1_b = (const float*)d_in[21];
  const float* cln_g = (const float*)d_in[22];
  const float* cln_b = (const float*)d_in[23];
  const float* cf2_w = (const float*)d_in[24];
  const float* cf2_b = (const float*)d_in[25];

  char* ws = (char*)d_ws;
  size_t off = 0;
  auto alloc = [&](size_t n) { char* r = ws + off; off += (n + 255) & ~(size_t)255; return r; };
  // weights (bf16, transposed) — 38 MiB
  u16* wqkv_t = (u16*)alloc((size_t)3072 * 1024 * 2);
  u16* sout_t = (u16*)alloc((size_t)1024 * 1024 * 2);
  u16* sf1_t = (u16*)alloc((size_t)2048 * 2048 * 2);
  u16* sf2_t = (u16*)alloc((size_t)1024 * 2048 * 2);
  u16* wcat_t = (u16*)alloc((size_t)2048 * 1024 * 2);
  u16* cout_t = (u16*)alloc((size_t)1024 * 1024 * 2);
  u16* cf1_t = (u16*)alloc((size_t)2048 * 2048 * 2);
  u16* cf2_t = (u16*)alloc((size_t)1024 * 2048 * 2);
  float* biascat = (float*)alloc(2048 * 4);
  // activations
  u16* CATb = (u16*)alloc((size_t)8192 * 2048 * 2);     // 32 MiB  [x | msg]
  char* BIG = alloc((size_t)8192 * 3072 * 2);           // 48 MiB  QKVbf / Hbf / CQKV
  char* QKB = alloc((size_t)3 * 8192 * 1024 * 2);       // 48 MiB  q,k,v ; G over q+k; CTX over v
  u16* VT = (u16*)alloc((size_t)64 * 64 * 2048 * 2);    // 16 MiB
  // total ~182 MiB

  u16* QKVbf = (u16*)BIG;
  u16* Hbf = (u16*)BIG;
  u16* CQKV = (u16*)BIG;
  u16* qB = (u16*)QKB;
  u16* kB = qB + (size_t)8192 * 1024;
  u16* vB = kB + (size_t)8192 * 1024;
  u16* G = (u16*)QKB;             // overlays qB+kB (dead after attention)
  u16* CTX = vB;                  // overlays vB (dead after vtrans)
  float* OUT = (float*)d_out;     // fp32 [8192][1024]; self-Y stored here, then
                                  // final gemm reads it as residual in-place

  hipStream_t st = stream;
  // weight prep
  wtrans<<<dim3(48, 16), 256, 0, st>>>(wqkv_w, wqkv_t, 1024, 3072);
  wtrans<<<dim3(16, 16), 256, 0, st>>>(sout_w, sout_t, 1024, 1024);
  wtrans<<<dim3(32, 32), 256, 0, st>>>(sf1_w, sf1_t, 2048, 2048);
  wtrans<<<dim3(16, 32), 256, 0, st>>>(sf2_w, sf2_t, 2048, 1024);
  wtrans<<<dim3(16, 16), 256, 0, st>>>(qk_w, wcat_t, 1024, 1024);
  wtrans<<<dim3(16, 16), 256, 0, st>>>(v_w, wcat_t + (size_t)1024 * 1024, 1024, 1024);
  wtrans<<<dim3(16, 16), 256, 0, st>>>(cout_w, cout_t, 1024, 1024);
  wtrans<<<dim3(32, 32), 256, 0, st>>>(cf1_w, cf1_t, 2048, 2048);
  wtrans<<<dim3(16, 32), 256, 0, st>>>(cf2_w, cf2_t, 2048, 1024);
  bias_cat2<<<8, 256, 0, st>>>(qk_b, v_b, biascat);
  prep_x<<<8192, 256, 0, st>>>(desc0, desc1, CATb);

  // ---- self blocks (batched desc0+desc1) ----
  gemm_bt<0, 1, 0><<<dim3(24, 64), 256, 0, st>>>(CATb, 2048, wqkv_t, 1024, wqkv_b, 1024,
                                                 nullptr, 0, QKVbf, 3072, 0, nullptr,
                                                 nullptr, 1 << 30, 0);
  rope_split<<<dim3(64, 16), 256, 0, st>>>(QKVbf, enc0, enc1, qB, kB, vB);
  vtrans<<<dim3(64, 32), 256, 0, st>>>(vB, 1024, 0, VT);
  attn_fa<<<dim3(32, 64), 256, 0, st>>>(qB, 1024, kB, 1024, VT, CTX, 0);
  gemm_bt<0, 1, 0><<<dim3(8, 64), 256, 0, st>>>(CTX, 1024, sout_t, 1024, sout_b, 1024,
                                                nullptr, 0, CATb, 2048, 1024, nullptr,
                                                nullptr, 1 << 30, 0);
  gemm_bt<0, 1, 0><<<dim3(16, 64), 256, 0, st>>>(CATb, 2048, sf1_t, 2048, sf1_b, 2048,
                                                 nullptr, 0, Hbf, 2048, 0, nullptr,
                                                 nullptr, 1 << 30, 0);
  ln_gelu<<<8192, 256, 0, st>>>(Hbf, sln_g, sln_b, G);
  gemm_bt<1, 1, 1><<<dim3(8, 64), 256, 0, st>>>(G, 2048, sf2_t, 2048, sf2_b, 2048,
                                                OUT, 1024, CATb, 2048, 0, desc0,
                                                desc1, 4096, 1024);

  // ---- cross block ----
  gemm_bt<0, 1, 0><<<dim3(16, 64), 256, 0, st>>>(CATb, 2048, wcat_t, 1024, biascat, 1024,
                                                 nullptr, 0, CQKV, 2048, 0, nullptr,
                                                 nullptr, 1 << 30, 0);
  vtrans<<<dim3(64, 32), 256, 0, st>>>(CQKV, 2048, 1024, VT);
  attn_fa<<<dim3(32, 64), 256, 0, st>>>(CQKV, 2048, CQKV, 2048, VT, CTX, 1);
  gemm_bt<0, 1, 0><<<dim3(8, 64), 256, 0, st>>>(CTX, 1024, cout_t, 1024, cout_b, 1024,
                                                nullptr, 0, CATb, 2048, 1024, nullptr,
                                                nullptr, 1 << 30, 0);
  gemm_bt<0, 1, 0><<<dim3(16, 64), 256, 0, st>>>(CATb, 2048, cf1_t, 2048, cf1_b, 2048,
                                                 nullptr, 0, Hbf, 2048, 0, nullptr,
                                                 nullptr, 1 << 30, 0);
  ln_gelu<<<8192, 256, 0, st>>>(Hbf, cln_g, cln_b, G);
  gemm_bt<1, 0, 1><<<dim3(8, 64), 256, 0, st>>>(G, 2048, cf2_t, 2048, cf2_b, 2048,
                                                OUT, 1024, nullptr, 0, 0, OUT,
                                                OUT, 1 << 30, 1024);
}

// Round 4
// 1147.162 us; speedup vs baseline: 1.2808x; 1.1942x over previous
//
#include <hip/hip_runtime.h>

// TransformerLayer on MI355X: 2x self-block (shared weights, batched) + cross-block.
// B=2, N=2048, D=1024, H=16, HD=64 -> M = 2*B*N = 8192 rows everywhere.
// R3 -> R4: attn_fa rewritten to 32x32 swapped-operand flash attention:
//   S = mfma(K,Q) so each lane owns one q-row's scores in registers;
//   softmax fully in-register (tree reduce + one shfl_xor(32));
//   P -> bf16 via v_cvt_pk_bf16_f32 + v_permlane32_swap_b32 (no LDS round trip);
//   PV = mfma(V^T, P) -> O^T so per-lane rescale is legal; exp in base-2 domain.

typedef unsigned short u16;
typedef unsigned int u32;
typedef float f32x4 __attribute__((ext_vector_type(4)));
typedef float f32x16 __attribute__((ext_vector_type(16)));
typedef __bf16 bf16x8 __attribute__((ext_vector_type(8)));
typedef u16 u16x2 __attribute__((ext_vector_type(2)));
typedef u16 u16x4 __attribute__((ext_vector_type(4)));
typedef u16 u16x8 __attribute__((ext_vector_type(8)));
typedef u32 u32x4 __attribute__((ext_vector_type(4)));

__device__ __forceinline__ u16 f2b(float f) {
  union { float f; unsigned u; } v; v.f = f;
  unsigned r = v.u + 0x7FFFu + ((v.u >> 16) & 1u);  // RNE
  return (u16)(r >> 16);
}
__device__ __forceinline__ float b2f(u16 s) {
  union { unsigned u; float f; } v; v.u = ((unsigned)s) << 16;
  return v.f;
}
__device__ __forceinline__ void gload16(const void* g, void* l) {
  __builtin_amdgcn_global_load_lds((const __attribute__((address_space(1))) void*)g,
                                   (__attribute__((address_space(3))) void*)l, 16, 0, 0);
}
__device__ __forceinline__ u32 cvtpk(float lo, float hi) {
  u32 r;
  asm("v_cvt_pk_bf16_f32 %0, %1, %2" : "=v"(r) : "v"(lo), "v"(hi));
  return r;
}
#define MFMA16(a, b, c) __builtin_amdgcn_mfma_f32_16x16x32_bf16(a, b, c, 0, 0, 0)
#define MFMA32(a, b, c) __builtin_amdgcn_mfma_f32_32x32x16_bf16(a, b, c, 0, 0, 0)

// ---------------------------------------------------------------------------
// Weight prep: fp32 [K][N] -> bf16 [N][K] (B^T layout for the GEMM)
// ---------------------------------------------------------------------------
__global__ __launch_bounds__(256) void wtrans(const float* __restrict__ src,
                                              u16* __restrict__ dst, int K, int N) {
  __shared__ __align__(16) u16 tile[64][72];
  const int k0 = blockIdx.y * 64, n0 = blockIdx.x * 64;
  const int t = threadIdx.x;
  {
    const int kl = t >> 2, nc = (t & 3) * 16;
    const float* sp = src + (size_t)(k0 + kl) * N + n0 + nc;
#pragma unroll
    for (int j = 0; j < 4; ++j) {
      float4 f = *(const float4*)(sp + j * 4);
      tile[kl][nc + j * 4 + 0] = f2b(f.x);
      tile[kl][nc + j * 4 + 1] = f2b(f.y);
      tile[kl][nc + j * 4 + 2] = f2b(f.z);
      tile[kl][nc + j * 4 + 3] = f2b(f.w);
    }
  }
  __syncthreads();
  {
    const int nl = t >> 2, kc = (t & 3) * 16;
    u16x8 o0, o1;
#pragma unroll
    for (int j = 0; j < 8; ++j) { o0[j] = tile[kc + j][nl]; o1[j] = tile[kc + 8 + j][nl]; }
    u16* dp = dst + (size_t)(n0 + nl) * K + k0 + kc;
    *(u16x8*)dp = o0;
    *(u16x8*)(dp + 8) = o1;
  }
}

__global__ void bias_cat2(const float* __restrict__ a, const float* __restrict__ b,
                          float* __restrict__ o) {
  int i = blockIdx.x * 256 + threadIdx.x;
  if (i < 2048) o[i] = (i < 1024) ? a[i] : b[i - 1024];
}

// desc0|desc1 -> CAT left half bf16 (ld 2048)
__global__ void prep_x(const float* __restrict__ d0, const float* __restrict__ d1,
                       u16* __restrict__ CAT) {
  size_t i4 = ((size_t)blockIdx.x * 256 + threadIdx.x) * 4;
  const float* src = (i4 < 4194304) ? (d0 + i4) : (d1 + (i4 - 4194304));
  float4 v = *(const float4*)src;
  size_t row = i4 >> 10, col = i4 & 1023;
  u16x4 o = {f2b(v.x), f2b(v.y), f2b(v.z), f2b(v.w)};
  *(u16x4*)(CAT + row * 2048 + col) = o;
}

// ---------------------------------------------------------------------------
// GEMM: C[M][N] = A[M][K](bf16) @ W[K][N] + bias;  B given as W^T [N][K] bf16.
// 128x128 tile, BK=32, 4 waves (2x2), 16 MFMA 16x16x32 per wave per K-step.
// ---------------------------------------------------------------------------
template <int WF32, int WBF16, int RES>
__global__ __launch_bounds__(256) void gemm_bt(
    const u16* __restrict__ A, int lda, const u16* __restrict__ Bt, int ldb,
    const float* __restrict__ bias, int K, float* __restrict__ outf, int ldf,
    u16* __restrict__ outb, int ldob, int coloff, const float* __restrict__ res,
    const float* __restrict__ res2, int rsplit, int ldr) {
  __shared__ __align__(16) u16 As[128 * 32];
  __shared__ __align__(16) u16 Bs[128 * 32];
  const int m0 = blockIdx.y * 128, n0 = blockIdx.x * 128;
  const int t = threadIdx.x;
  const int w = t >> 6, l = t & 63;
  const int wr = (w >> 1) * 64, wc = (w & 1) * 64;
  const int lr = l & 15, lg = l >> 4;
  f32x4 acc[4][4] = {};
  const u16* Ab = A + (size_t)m0 * lda;
  const u16* Bb = Bt + (size_t)n0 * ldb;
  const int srow = t >> 2;
  const int scol = (t & 3) * 8;
  for (int k0 = 0; k0 < K; k0 += 32) {
    gload16(Ab + (size_t)srow * lda + k0 + scol, &As[srow * 32 + scol]);
    gload16(Ab + (size_t)(srow + 64) * lda + k0 + scol, &As[(srow + 64) * 32 + scol]);
    gload16(Bb + (size_t)srow * ldb + k0 + scol, &Bs[srow * 32 + scol]);
    gload16(Bb + (size_t)(srow + 64) * ldb + k0 + scol, &Bs[(srow + 64) * 32 + scol]);
    __syncthreads();
    bf16x8 af[4], bfr[4];
#pragma unroll
    for (int m = 0; m < 4; ++m) af[m] = *(const bf16x8*)&As[(wr + m * 16 + lr) * 32 + lg * 8];
#pragma unroll
    for (int n = 0; n < 4; ++n) bfr[n] = *(const bf16x8*)&Bs[(wc + n * 16 + lr) * 32 + lg * 8];
#pragma unroll
    for (int m = 0; m < 4; ++m)
#pragma unroll
      for (int n = 0; n < 4; ++n) acc[m][n] = MFMA16(af[m], bfr[n], acc[m][n]);
    __syncthreads();
  }
#pragma unroll
  for (int m = 0; m < 4; ++m) {
#pragma unroll
    for (int n = 0; n < 4; ++n) {
#pragma unroll
      for (int r = 0; r < 4; ++r) {
        const int row = m0 + wr + m * 16 + lg * 4 + r;
        const int col = n0 + wc + n * 16 + lr;
        float v = acc[m][n][r] + bias[col];
        if (RES) {
          const float* rp = res;
          int rr = row;
          if (row >= rsplit) { rp = res2; rr = row - rsplit; }
          v += rp[(size_t)rr * ldr + col];
        }
        if (WF32) outf[(size_t)row * ldf + col] = v;
        if (WBF16) outb[(size_t)row * ldob + coloff + col] = f2b(v);
      }
    }
  }
}

// ---------------------------------------------------------------------------
// QKV split + RoPE.  QKV bf16 [8192][3072], col = h*192 + d*3 + {0:q,1:k,2:v}.
// ---------------------------------------------------------------------------
__global__ __launch_bounds__(256) void rope_split(
    const u16* __restrict__ QKV, const float* __restrict__ enc0,
    const float* __restrict__ enc1, u16* __restrict__ qo, u16* __restrict__ ko,
    u16* __restrict__ vo) {
  const int p = blockIdx.x, nt = blockIdx.y;
  const int bdb = p >> 4, h = p & 15;
  const int t = threadIdx.x;
  const int ip = t & 31, nl = t >> 5;
  const float* enc = (bdb < 2) ? enc0 : enc1;
  const float* e0base = enc + (size_t)(bdb & 1) * 131072 + ip * 2;  // [2,B,1,N,64]
#pragma unroll 4
  for (int it = 0; it < 16; ++it) {
    const int n = nt * 128 + it * 8 + nl;
    const size_t row = (size_t)bdb * 2048 + n;
    const unsigned* su = (const unsigned*)(QKV + row * 3072 + h * 192 + ip * 6);
    const unsigned u0 = su[0], u1 = su[1], u2 = su[2];
    const float qe = b2f((u16)u0), ke = b2f((u16)(u0 >> 16));
    const u16 vbe = (u16)u1;
    const float qot = b2f((u16)(u1 >> 16));
    const float kot = b2f((u16)u2);
    const u16 vbo = (u16)(u2 >> 16);
    const float* ep = e0base + (size_t)n * 64;
    const float2 f0 = *(const float2*)ep;
    const float2 f1 = *(const float2*)(ep + 262144);
    u16x2 qw = {f2b(qe * f0.x - qot * f1.x), f2b(qot * f0.y + qe * f1.y)};
    u16x2 kw = {f2b(ke * f0.x - kot * f1.x), f2b(kot * f0.y + ke * f1.y)};
    u16x2 vw = {vbe, vbo};
    const size_t ob = row * 1024 + h * 64 + ip * 2;
    *(u16x2*)(qo + ob) = qw;
    *(u16x2*)(ko + ob) = kw;
    *(u16x2*)(vo + ob) = vw;
  }
}

// per-head V transpose: in [8192][in_ld] bf16 -> out [64 problems][64 d][2048 n]
__global__ __launch_bounds__(256) void vtrans(const u16* __restrict__ in, int in_ld,
                                              int col_off, u16* __restrict__ out) {
  const int p = blockIdx.x, nt = blockIdx.y;
  const int bdb = p >> 4, h = p & 15;
  const int t = threadIdx.x;
  __shared__ __align__(16) u16 tile[64][72];
  {
    const int nl = t >> 2, dc = (t & 3) * 16;
    const u16* sp = in + (size_t)(bdb * 2048 + nt * 64 + nl) * in_ld + col_off + h * 64 + dc;
    u16x8 a = *(const u16x8*)sp;
    u16x8 b = *(const u16x8*)(sp + 8);
#pragma unroll
    for (int j = 0; j < 8; ++j) { tile[nl][dc + j] = a[j]; tile[nl][dc + 8 + j] = b[j]; }
  }
  __syncthreads();
  {
    const int d = t >> 2, nc = (t & 3) * 16;
    u16x8 o0, o1;
#pragma unroll
    for (int j = 0; j < 8; ++j) { o0[j] = tile[nc + j][d]; o1[j] = tile[nc + 8 + j][d]; }
    u16* dp = out + (size_t)p * 131072 + (size_t)d * 2048 + nt * 64 + nc;
    *(u16x8*)dp = o0;
    *(u16x8*)(dp + 8) = o1;
  }
}

// ---------------------------------------------------------------------------
// Flash attention, HD=64, N=2048, scale=1/8.  4 waves x 32 q-rows, KVBLK=64.
// Swapped operands: S = mfma(K,Q) (lane owns q-row = lane&31, k in 2 accs +
// lane pair);  P packed in-register via cvt_pk + permlane32_swap;
// O^T = mfma(V^T, P).  K/V double-buffered, XOR-swizzled LDS.
// ---------------------------------------------------------------------------
__global__ __launch_bounds__(256) void attn_fa(const u16* __restrict__ qbase, int q_ld,
                                               const u16* __restrict__ kbase, int k_ld,
                                               const u16* __restrict__ vtbase,
                                               u16* __restrict__ ctxbase, int mode) {
  const int qb = blockIdx.x;  // 0..15
  const int p = blockIdx.y;   // 0..63
  const int t = threadIdx.x, w = t >> 6, l = t & 63;
  const int lq = l & 31;      // this lane's q-row (and V^T d-row for PV reads)
  const int hi = l >> 5;      // contraction half select
  const int hi8 = hi * 8;

  const u16 *qp, *kp, *vtp;
  u16* op;
  if (mode == 0) {
    const int bdb = p >> 4, h = p & 15;
    const size_t rb = (size_t)bdb * 2048;
    qp = qbase + rb * q_ld + h * 64;
    kp = kbase + rb * k_ld + h * 64;
    vtp = vtbase + (size_t)p * 131072;
    op = ctxbase + rb * 1024 + h * 64;
  } else {
    const int bd = p >> 5, b = (p >> 4) & 1, h = p & 15;
    const size_t qrb = (size_t)bd * 4096 + (size_t)b * 2048;
    const size_t krb = (size_t)(1 - bd) * 4096 + (size_t)b * 2048;
    qp = qbase + qrb * q_ld + h * 64;
    kp = kbase + krb * k_ld + h * 64;
    const int pv = ((1 - bd) * 2 + b) * 16 + h;
    vtp = vtbase + (size_t)pv * 131072;
    op = ctxbase + qrb * 1024 + h * 64;
  }

  __shared__ __align__(16) u16 kbuf[2][64 * 64];
  __shared__ __align__(16) u16 vbuf[2][64 * 64];

  // Q fragments (B-operand of S=K*Q): lane needs Q[qrow][dc*16 + hi*8 + j]
  const int qrow = qb * 128 + w * 32 + lq;
  bf16x8 qf[4];
#pragma unroll
  for (int dc = 0; dc < 4; ++dc)
    qf[dc] = *(const bf16x8*)(qp + (size_t)qrow * q_ld + dc * 16 + hi8);

  f32x16 accO0 = {}, accO1 = {};
  float m2 = -1e30f, lrun = 0.f;
  const float SC = 0.18033688011116044f;  // 0.125 * log2(e)

  // staging geometry: linear LDS dest, pre-swizzled global source column so
  // that LDS[row][c8] holds global[row][c8 ^ (row&7)] (16B granules).
  const int sr0 = t >> 3;
  const int sc8 = ((t & 7) ^ (sr0 & 7)) * 8;
  const int ldst = sr0 * 64 + (t & 7) * 8;
  const int swz = (lq & 7) << 3;  // read-side XOR (u16 units); rows lq,lq+32 share it

  gload16(kp + (size_t)sr0 * k_ld + sc8, &kbuf[0][ldst]);
  gload16(kp + (size_t)(sr0 + 32) * k_ld + sc8, &kbuf[0][ldst + 2048]);
  gload16(vtp + (size_t)sr0 * 2048 + sc8, &vbuf[0][ldst]);
  gload16(vtp + (size_t)(sr0 + 32) * 2048 + sc8, &vbuf[0][ldst + 2048]);
  __syncthreads();

  for (int it = 0; it < 32; ++it) {
    const int cur = it & 1;
    if (it < 31) {  // stage next tile (overlaps compute; drained by barrier)
      const int kt = (it + 1) * 64;
      u16* kd = &kbuf[cur ^ 1][ldst];
      u16* vd = &vbuf[cur ^ 1][ldst];
      gload16(kp + (size_t)(kt + sr0) * k_ld + sc8, kd);
      gload16(kp + (size_t)(kt + sr0 + 32) * k_ld + sc8, kd + 2048);
      gload16(vtp + (size_t)sr0 * 2048 + kt + sc8, vd);
      gload16(vtp + (size_t)(sr0 + 32) * 2048 + kt + sc8, vd + 2048);
    }
    const u16* kb = kbuf[cur];
    const u16* vb = vbuf[cur];

    // S = K * Q : s0 covers k-rows 0..31, s1 k-rows 32..63 (cols = q)
    f32x16 s0 = {}, s1 = {};
    __builtin_amdgcn_s_setprio(1);
#pragma unroll
    for (int dc = 0; dc < 4; ++dc) {
      const int off = (dc * 16 + hi8) ^ swz;
      const bf16x8 ka0 = *(const bf16x8*)&kb[lq * 64 + off];
      const bf16x8 ka1 = *(const bf16x8*)&kb[(lq + 32) * 64 + off];
      s0 = MFMA32(ka0, qf[dc], s0);
      s1 = MFMA32(ka1, qf[dc], s1);
    }
    __builtin_amdgcn_s_setprio(0);

    // ---- in-register online softmax (q-row = lane&31; pair lane l^32) ----
    float tm[8];
#pragma unroll
    for (int j = 0; j < 8; ++j)
      tm[j] = fmaxf(fmaxf(s0[j], s0[j + 8]), fmaxf(s1[j], s1[j + 8]));
    float mr = fmaxf(fmaxf(fmaxf(tm[0], tm[1]), fmaxf(tm[2], tm[3])),
                     fmaxf(fmaxf(tm[4], tm[5]), fmaxf(tm[6], tm[7])));
    mr = fmaxf(mr, __shfl_xor(mr, 32));
    const float m2new = fmaxf(m2, mr * SC);
    const float al = __builtin_amdgcn_exp2f(m2 - m2new);
    m2 = m2new;
    f32x16 p0, p1;
#pragma unroll
    for (int r = 0; r < 16; ++r) p0[r] = __builtin_amdgcn_exp2f(fmaf(s0[r], SC, -m2new));
#pragma unroll
    for (int r = 0; r < 16; ++r) p1[r] = __builtin_amdgcn_exp2f(fmaf(s1[r], SC, -m2new));
    const f32x16 ts = p0 + p1;
    float sa[8];
#pragma unroll
    for (int j = 0; j < 8; ++j) sa[j] = ts[j] + ts[j + 8];
    float rs = ((sa[0] + sa[1]) + (sa[2] + sa[3])) + ((sa[4] + sa[5]) + (sa[6] + sa[7]));
    rs += __shfl_xor(rs, 32);
    lrun = lrun * al + rs;
    accO0 *= al;
    accO1 *= al;

    // ---- pack P to bf16 B-fragments (4 chunks of k=16) ----
    bf16x8 paf[4];
#pragma unroll
    for (int kc = 0; kc < 4; ++kc) {
      const f32x16& ps = (kc < 2) ? p0 : p1;
      const int b0 = (kc & 1) * 8;
      u32 a = cvtpk(ps[b0 + 0], ps[b0 + 1]);
      u32 c = cvtpk(ps[b0 + 2], ps[b0 + 3]);
      u32 b = cvtpk(ps[b0 + 4], ps[b0 + 5]);
      u32 d = cvtpk(ps[b0 + 6], ps[b0 + 7]);
      asm("v_permlane32_swap_b32 %0, %1" : "+v"(a), "+v"(b));
      asm("v_permlane32_swap_b32 %0, %1" : "+v"(c), "+v"(d));
      u32x4 wv = {a, c, b, d};
      paf[kc] = __builtin_bit_cast(bf16x8, wv);
    }

    // ---- O^T += V^T * P  (rows = d, cols = q = lane&31) ----
    __builtin_amdgcn_s_setprio(1);
#pragma unroll
    for (int kc = 0; kc < 4; ++kc) {
      const int off = (kc * 16 + hi8) ^ swz;
      const bf16x8 va0 = *(const bf16x8*)&vb[lq * 64 + off];
      const bf16x8 va1 = *(const bf16x8*)&vb[(lq + 32) * 64 + off];
      accO0 = MFMA32(va0, paf[kc], accO0);
      accO1 = MFMA32(va1, paf[kc], accO1);
    }
    __builtin_amdgcn_s_setprio(0);
    __syncthreads();
  }

  const float inv = 1.f / lrun;
  accO0 *= inv;
  accO1 *= inv;
  u16* orow = op + (size_t)qrow * 1024;
#pragma unroll
  for (int r = 0; r < 16; r += 2) {
    const int d = (r & 3) + 8 * (r >> 2) + 4 * hi;
    *(u32*)&orow[d] = cvtpk(accO0[r], accO0[r + 1]);
    *(u32*)&orow[d + 32] = cvtpk(accO1[r], accO1[r + 1]);
  }
}

// ---------------------------------------------------------------------------
// LayerNorm (over 2048) + exact GELU, bf16 in -> bf16 out (stats in fp32)
// ---------------------------------------------------------------------------
__global__ __launch_bounds__(256) void ln_gelu(const u16* __restrict__ H,
                                               const float* __restrict__ gam,
                                               const float* __restrict__ bet,
                                               u16* __restrict__ G) {
  const int row = blockIdx.x, t = threadIdx.x;
  u16x8 hv = *(const u16x8*)(H + (size_t)row * 2048 + t * 8);
  float v[8];
#pragma unroll
  for (int j = 0; j < 8; ++j) v[j] = b2f(hv[j]);
  float s = 0.f, s2 = 0.f;
#pragma unroll
  for (int j = 0; j < 8; ++j) { s += v[j]; s2 += v[j] * v[j]; }
#pragma unroll
  for (int off = 32; off; off >>= 1) { s += __shfl_xor(s, off); s2 += __shfl_xor(s2, off); }
  __shared__ float red[8];
  const int w = t >> 6, l = t & 63;
  if (l == 0) { red[w] = s; red[4 + w] = s2; }
  __syncthreads();
  s = red[0] + red[1] + red[2] + red[3];
  s2 = red[4] + red[5] + red[6] + red[7];
  const float mean = s * (1.f / 2048.f);
  const float rstd = rsqrtf(s2 * (1.f / 2048.f) - mean * mean + 1e-5f);
  u16x8 o;
#pragma unroll
  for (int j = 0; j < 8; ++j) {
    const int col = t * 8 + j;
    const float x = (v[j] - mean) * rstd * gam[col] + bet[col];
    o[j] = f2b(x * 0.5f * (1.f + erff(x * 0.7071067811865475f)));
  }
  *(u16x8*)(G + (size_t)row * 2048 + t * 8) = o;
}

// ---------------------------------------------------------------------------
extern "C" void kernel_launch(void* const* d_in, const int* in_sizes, int n_in,
                              void* d_out, int out_size, void* d_ws, size_t ws_size,
                              hipStream_t stream) {
  (void)in_sizes; (void)n_in; (void)out_size; (void)ws_size;
  const float* desc0 = (const float*)d_in[0];
  const float* desc1 = (const float*)d_in[1];
  const float* enc0 = (const float*)d_in[2];
  const float* enc1 = (const float*)d_in[3];
  const float* wqkv_w = (const float*)d_in[4];
  const float* wqkv_b = (const float*)d_in[5];
  const float* sout_w = (const float*)d_in[6];
  const float* sout_b = (const float*)d_in[7];
  const float* sf1_w = (const float*)d_in[8];
  const float* sf1_b = (const float*)d_in[9];
  const float* sln_g = (const float*)d_in[10];
  const float* sln_b = (const float*)d_in[11];
  const float* sf2_w = (const float*)d_in[12];
  const float* sf2_b = (const float*)d_in[13];
  const float* qk_w = (const float*)d_in[14];
  const float* qk_b = (const float*)d_in[15];
  const float* v_w = (const float*)d_in[16];
  const float* v_b = (const float*)d_in[17];
  const float* cout_w = (const float*)d_in[18];
  const float* cout_b = (const float*)d_in[19];
  const float* cf1_w = (const float*)d_in[20];
  const float* cf1_b = (const float*)d_in[21];
  const float* cln_g = (const float*)d_in[22];
  const float* cln_b = (const float*)d_in[23];
  const float* cf2_w = (const float*)d_in[24];
  const float* cf2_b = (const float*)d_in[25];

  char* ws = (char*)d_ws;
  size_t off = 0;
  auto alloc = [&](size_t n) { char* r = ws + off; off += (n + 255) & ~(size_t)255; return r; };
  // weights (bf16, transposed) — 38 MiB
  u16* wqkv_t = (u16*)alloc((size_t)3072 * 1024 * 2);
  u16* sout_t = (u16*)alloc((size_t)1024 * 1024 * 2);
  u16* sf1_t = (u16*)alloc((size_t)2048 * 2048 * 2);
  u16* sf2_t = (u16*)alloc((size_t)1024 * 2048 * 2);
  u16* wcat_t = (u16*)alloc((size_t)2048 * 1024 * 2);
  u16* cout_t = (u16*)alloc((size_t)1024 * 1024 * 2);
  u16* cf1_t = (u16*)alloc((size_t)2048 * 2048 * 2);
  u16* cf2_t = (u16*)alloc((size_t)1024 * 2048 * 2);
  float* biascat = (float*)alloc(2048 * 4);
  // activations
  u16* CATb = (u16*)alloc((size_t)8192 * 2048 * 2);     // 32 MiB  [x | msg]
  char* BIG = alloc((size_t)8192 * 3072 * 2);           // 48 MiB  QKVbf / Hbf / CQKV
  char* QKB = alloc((size_t)3 * 8192 * 1024 * 2);       // 48 MiB  q,k,v ; G over q+k; CTX over v
  u16* VT = (u16*)alloc((size_t)64 * 64 * 2048 * 2);    // 16 MiB
  // total ~182 MiB

  u16* QKVbf = (u16*)BIG;
  u16* Hbf = (u16*)BIG;
  u16* CQKV = (u16*)BIG;
  u16* qB = (u16*)QKB;
  u16* kB = qB + (size_t)8192 * 1024;
  u16* vB = kB + (size_t)8192 * 1024;
  u16* G = (u16*)QKB;             // overlays qB+kB (dead after attention)
  u16* CTX = vB;                  // overlays vB (dead after vtrans)
  float* OUT = (float*)d_out;     // fp32 [8192][1024]; self-Y stored here, then
                                  // final gemm reads it as residual in-place

  hipStream_t st = stream;
  // weight prep
  wtrans<<<dim3(48, 16), 256, 0, st>>>(wqkv_w, wqkv_t, 1024, 3072);
  wtrans<<<dim3(16, 16), 256, 0, st>>>(sout_w, sout_t, 1024, 1024);
  wtrans<<<dim3(32, 32), 256, 0, st>>>(sf1_w, sf1_t, 2048, 2048);
  wtrans<<<dim3(16, 32), 256, 0, st>>>(sf2_w, sf2_t, 2048, 1024);
  wtrans<<<dim3(16, 16), 256, 0, st>>>(qk_w, wcat_t, 1024, 1024);
  wtrans<<<dim3(16, 16), 256, 0, st>>>(v_w, wcat_t + (size_t)1024 * 1024, 1024, 1024);
  wtrans<<<dim3(16, 16), 256, 0, st>>>(cout_w, cout_t, 1024, 1024);
  wtrans<<<dim3(32, 32), 256, 0, st>>>(cf1_w, cf1_t, 2048, 2048);
  wtrans<<<dim3(16, 32), 256, 0, st>>>(cf2_w, cf2_t, 2048, 1024);
  bias_cat2<<<8, 256, 0, st>>>(qk_b, v_b, biascat);
  prep_x<<<8192, 256, 0, st>>>(desc0, desc1, CATb);

  // ---- self blocks (batched desc0+desc1) ----
  gemm_bt<0, 1, 0><<<dim3(24, 64), 256, 0, st>>>(CATb, 2048, wqkv_t, 1024, wqkv_b, 1024,
                                                 nullptr, 0, QKVbf, 3072, 0, nullptr,
                                                 nullptr, 1 << 30, 0);
  rope_split<<<dim3(64, 16), 256, 0, st>>>(QKVbf, enc0, enc1, qB, kB, vB);
  vtrans<<<dim3(64, 32), 256, 0, st>>>(vB, 1024, 0, VT);
  attn_fa<<<dim3(16, 64), 256, 0, st>>>(qB, 1024, kB, 1024, VT, CTX, 0);
  gemm_bt<0, 1, 0><<<dim3(8, 64), 256, 0, st>>>(CTX, 1024, sout_t, 1024, sout_b, 1024,
                                                nullptr, 0, CATb, 2048, 1024, nullptr,
                                                nullptr, 1 << 30, 0);
  gemm_bt<0, 1, 0><<<dim3(16, 64), 256, 0, st>>>(CATb, 2048, sf1_t, 2048, sf1_b, 2048,
                                                 nullptr, 0, Hbf, 2048, 0, nullptr,
                                                 nullptr, 1 << 30, 0);
  ln_gelu<<<8192, 256, 0, st>>>(Hbf, sln_g, sln_b, G);
  gemm_bt<1, 1, 1><<<dim3(8, 64), 256, 0, st>>>(G, 2048, sf2_t, 2048, sf2_b, 2048,
                                                OUT, 1024, CATb, 2048, 0, desc0,
                                                desc1, 4096, 1024);

  // ---- cross block ----
  gemm_bt<0, 1, 0><<<dim3(16, 64), 256, 0, st>>>(CATb, 2048, wcat_t, 1024, biascat, 1024,
                                                 nullptr, 0, CQKV, 2048, 0, nullptr,
                                                 nullptr, 1 << 30, 0);
  vtrans<<<dim3(64, 32), 256, 0, st>>>(CQKV, 2048, 1024, VT);
  attn_fa<<<dim3(16, 64), 256, 0, st>>>(CQKV, 2048, CQKV, 2048, VT, CTX, 1);
  gemm_bt<0, 1, 0><<<dim3(8, 64), 256, 0, st>>>(CTX, 1024, cout_t, 1024, cout_b, 1024,
                                                nullptr, 0, CATb, 2048, 1024, nullptr,
                                                nullptr, 1 << 30, 0);
  gemm_bt<0, 1, 0><<<dim3(16, 64), 256, 0, st>>>(CATb, 2048, cf1_t, 2048, cf1_b, 2048,
                                                 nullptr, 0, Hbf, 2048, 0, nullptr,
                                                 nullptr, 1 << 30, 0);
  ln_gelu<<<8192, 256, 0, st>>>(Hbf, cln_g, cln_b, G);
  gemm_bt<1, 0, 1><<<dim3(8, 64), 256, 0, st>>>(G, 2048, cf2_t, 2048, cf2_b, 2048,
                                                OUT, 1024, nullptr, 0, 0, OUT,
                                                OUT, 1 << 30, 1024);
}

// Round 5
// 1025.501 us; speedup vs baseline: 1.4327x; 1.1186x over previous
//
#include <hip/hip_runtime.h>

// TransformerLayer on MI355X: 2x self-block (shared weights, batched) + cross-block.
// B=2, N=2048, D=1024, H=16, HD=64 -> M = 2*B*N = 8192 rows everywhere.
// R4 -> R5: GEMMs moved to gemm8: 256-wide tile, 8 waves, BK=32, 3-buffer LDS
// ring with 2-tile-ahead prefetch and counted s_waitcnt vmcnt(L) (never 0 in
// the main loop), raw s_barrier (1 per K-tile), T2 swizzle, T1 XCD swizzle.

typedef unsigned short u16;
typedef unsigned int u32;
typedef float f32x4 __attribute__((ext_vector_type(4)));
typedef float f32x16 __attribute__((ext_vector_type(16)));
typedef __bf16 bf16x8 __attribute__((ext_vector_type(8)));
typedef u16 u16x2 __attribute__((ext_vector_type(2)));
typedef u16 u16x4 __attribute__((ext_vector_type(4)));
typedef u16 u16x8 __attribute__((ext_vector_type(8)));
typedef u32 u32x4 __attribute__((ext_vector_type(4)));

__device__ __forceinline__ u16 f2b(float f) {
  union { float f; unsigned u; } v; v.f = f;
  unsigned r = v.u + 0x7FFFu + ((v.u >> 16) & 1u);  // RNE
  return (u16)(r >> 16);
}
__device__ __forceinline__ float b2f(u16 s) {
  union { unsigned u; float f; } v; v.u = ((unsigned)s) << 16;
  return v.f;
}
__device__ __forceinline__ void gload16(const void* g, void* l) {
  __builtin_amdgcn_global_load_lds((const __attribute__((address_space(1))) void*)g,
                                   (__attribute__((address_space(3))) void*)l, 16, 0, 0);
}
__device__ __forceinline__ u32 cvtpk(float lo, float hi) {
  u32 r;
  asm("v_cvt_pk_bf16_f32 %0, %1, %2" : "=v"(r) : "v"(lo), "v"(hi));
  return r;
}
template <int N> __device__ __forceinline__ void waitvm() {
  if constexpr (N == 0) asm volatile("s_waitcnt vmcnt(0)" ::: "memory");
  else if constexpr (N == 3) asm volatile("s_waitcnt vmcnt(3)" ::: "memory");
  else asm volatile("s_waitcnt vmcnt(4)" ::: "memory");
}
#define MFMA16(a, b, c) __builtin_amdgcn_mfma_f32_16x16x32_bf16(a, b, c, 0, 0, 0)
#define MFMA32(a, b, c) __builtin_amdgcn_mfma_f32_32x32x16_bf16(a, b, c, 0, 0, 0)

// ---------------------------------------------------------------------------
// Weight prep: fp32 [K][N] -> bf16 [N][K] (B^T layout for the GEMM)
// ---------------------------------------------------------------------------
__global__ __launch_bounds__(256) void wtrans(const float* __restrict__ src,
                                              u16* __restrict__ dst, int K, int N) {
  __shared__ __align__(16) u16 tile[64][72];
  const int k0 = blockIdx.y * 64, n0 = blockIdx.x * 64;
  const int t = threadIdx.x;
  {
    const int kl = t >> 2, nc = (t & 3) * 16;
    const float* sp = src + (size_t)(k0 + kl) * N + n0 + nc;
#pragma unroll
    for (int j = 0; j < 4; ++j) {
      float4 f = *(const float4*)(sp + j * 4);
      tile[kl][nc + j * 4 + 0] = f2b(f.x);
      tile[kl][nc + j * 4 + 1] = f2b(f.y);
      tile[kl][nc + j * 4 + 2] = f2b(f.z);
      tile[kl][nc + j * 4 + 3] = f2b(f.w);
    }
  }
  __syncthreads();
  {
    const int nl = t >> 2, kc = (t & 3) * 16;
    u16x8 o0, o1;
#pragma unroll
    for (int j = 0; j < 8; ++j) { o0[j] = tile[kc + j][nl]; o1[j] = tile[kc + 8 + j][nl]; }
    u16* dp = dst + (size_t)(n0 + nl) * K + k0 + kc;
    *(u16x8*)dp = o0;
    *(u16x8*)(dp + 8) = o1;
  }
}

__global__ void bias_cat2(const float* __restrict__ a, const float* __restrict__ b,
                          float* __restrict__ o) {
  int i = blockIdx.x * 256 + threadIdx.x;
  if (i < 2048) o[i] = (i < 1024) ? a[i] : b[i - 1024];
}

// desc0|desc1 -> CAT left half bf16 (ld 2048)
__global__ void prep_x(const float* __restrict__ d0, const float* __restrict__ d1,
                       u16* __restrict__ CAT) {
  size_t i4 = ((size_t)blockIdx.x * 256 + threadIdx.x) * 4;
  const float* src = (i4 < 4194304) ? (d0 + i4) : (d1 + (i4 - 4194304));
  float4 v = *(const float4*)src;
  size_t row = i4 >> 10, col = i4 & 1023;
  u16x4 o = {f2b(v.x), f2b(v.y), f2b(v.z), f2b(v.w)};
  *(u16x4*)(CAT + row * 2048 + col) = o;
}

// ---------------------------------------------------------------------------
// gemm8: C[M][N] = A[M][K](bf16) @ W[K][N] + bias;  W given transposed [N][K].
// BM=256, BN in {256,128}, BK=32, 512 threads (8 waves, 2Mx4N).
// 3-buffer LDS ring, 2-tile-ahead prefetch, counted vmcnt, 1 barrier/tile.
// LDS layout swizzled: LDS[row][slot] = global[row][slot ^ ((row>>1)&3)]
// (slots are 16B granules; staged via pre-swizzled global source column).
// ---------------------------------------------------------------------------
template <int BN, int WF32, int WBF16, int RES>
__global__ __launch_bounds__(512, 2) void gemm8(
    const u16* __restrict__ A, int lda, const u16* __restrict__ Bt, int ldb,
    const float* __restrict__ bias, int K, float* outf, int ldf,
    u16* __restrict__ outb, int ldob, int coloff, const float* res,
    const float* res2, int rsplit, int ldr) {
  constexpr int ASZ = 256 * 32;  // u16
  constexpr int BSZ = BN * 32;
  constexpr int BUF = ASZ + BSZ;
  constexpr int L = (BN == 256) ? 4 : 3;  // gloads per tile per thread
  constexpr int NR = BN / 64;             // n-fragments per wave
  __shared__ __align__(16) u16 lds[3 * BUF];

  // T1: bijective XCD swizzle of the linear block id (all grids %8==0)
  const int gx = gridDim.x, nwg = gx * gridDim.y;
  int id = blockIdx.y * gx + blockIdx.x;
  id = (id & 7) * (nwg >> 3) + (id >> 3);
  const int bx = id % gx, by = id / gx;
  const int m0 = by * 256, n0 = bx * BN;

  const int t = threadIdx.x;
  const int w = t >> 6, l = t & 63;
  const int wm = w >> 2, wn = w & 3;
  const int lr = l & 15, lg = l >> 4;

  const int r4 = t >> 2, s4 = t & 3;
  const int ssw = ((s4 ^ ((r4 >> 1) & 3)) * 8);  // pre-swizzled source col (u16)
  const int dst = r4 * 32 + s4 * 8;              // linear LDS dest (u16)
  const u16* Abase = A + (size_t)m0 * lda;
  const u16* Bbase = Bt + (size_t)n0 * ldb;

  auto stage = [&](int tt, u16* buf) {
    const int k0 = tt * 32;
    gload16(Abase + (size_t)r4 * lda + k0 + ssw, buf + dst);
    gload16(Abase + (size_t)(r4 + 128) * lda + k0 + ssw, buf + dst + 128 * 32);
    u16* bb = buf + ASZ;
    gload16(Bbase + (size_t)r4 * ldb + k0 + ssw, bb + dst);
    if constexpr (BN == 256)
      gload16(Bbase + (size_t)(r4 + 128) * ldb + k0 + ssw, bb + dst + 128 * 32);
  };

  const int cA = (lg ^ ((lr >> 1) & 3)) * 8;  // swizzled read col (u16)
  f32x4 acc[8][NR] = {};
  const int nt = K >> 5;

  stage(0, lds);
  stage(1, lds + BUF);
  waitvm<L>();
  __builtin_amdgcn_s_barrier();

  for (int tt = 0; tt < nt; ++tt) {
    u16* buf = lds + (tt % 3) * BUF;
    if (tt + 2 < nt) stage(tt + 2, lds + ((tt + 2) % 3) * BUF);
    const u16* As = buf;
    const u16* Bs = buf + ASZ;
    bf16x8 af[8], bfr[NR];
#pragma unroll
    for (int m = 0; m < 8; ++m)
      af[m] = *(const bf16x8*)&As[(wm * 128 + m * 16 + lr) * 32 + cA];
#pragma unroll
    for (int n = 0; n < NR; ++n)
      bfr[n] = *(const bf16x8*)&Bs[(wn * (NR * 16) + n * 16 + lr) * 32 + cA];
#pragma unroll
    for (int m = 0; m < 8; ++m)
#pragma unroll
      for (int n = 0; n < NR; ++n) acc[m][n] = MFMA16(af[m], bfr[n], acc[m][n]);
    if (tt + 2 < nt) {
      waitvm<L>();
      __builtin_amdgcn_s_barrier();
    } else if (tt + 1 < nt) {
      waitvm<0>();
      __builtin_amdgcn_s_barrier();
    }
  }

#pragma unroll
  for (int m = 0; m < 8; ++m) {
#pragma unroll
    for (int n = 0; n < NR; ++n) {
#pragma unroll
      for (int r = 0; r < 4; ++r) {
        const int row = m0 + wm * 128 + m * 16 + lg * 4 + r;
        const int col = n0 + wn * (NR * 16) + n * 16 + lr;
        float v = acc[m][n][r] + bias[col];
        if (RES) {
          const float* rp = res;
          int rr = row;
          if (row >= rsplit) { rp = res2; rr = row - rsplit; }
          v += rp[(size_t)rr * ldr + col];
        }
        if (WF32) outf[(size_t)row * ldf + col] = v;
        if (WBF16) outb[(size_t)row * ldob + coloff + col] = f2b(v);
      }
    }
  }
}

// ---------------------------------------------------------------------------
// QKV split + RoPE.  QKV bf16 [8192][3072], col = h*192 + d*3 + {0:q,1:k,2:v}.
// ---------------------------------------------------------------------------
__global__ __launch_bounds__(256) void rope_split(
    const u16* __restrict__ QKV, const float* __restrict__ enc0,
    const float* __restrict__ enc1, u16* __restrict__ qo, u16* __restrict__ ko,
    u16* __restrict__ vo) {
  const int p = blockIdx.x, nt = blockIdx.y;
  const int bdb = p >> 4, h = p & 15;
  const int t = threadIdx.x;
  const int ip = t & 31, nl = t >> 5;
  const float* enc = (bdb < 2) ? enc0 : enc1;
  const float* e0base = enc + (size_t)(bdb & 1) * 131072 + ip * 2;  // [2,B,1,N,64]
#pragma unroll 4
  for (int it = 0; it < 16; ++it) {
    const int n = nt * 128 + it * 8 + nl;
    const size_t row = (size_t)bdb * 2048 + n;
    const unsigned* su = (const unsigned*)(QKV + row * 3072 + h * 192 + ip * 6);
    const unsigned u0 = su[0], u1 = su[1], u2 = su[2];
    const float qe = b2f((u16)u0), ke = b2f((u16)(u0 >> 16));
    const u16 vbe = (u16)u1;
    const float qot = b2f((u16)(u1 >> 16));
    const float kot = b2f((u16)u2);
    const u16 vbo = (u16)(u2 >> 16);
    const float* ep = e0base + (size_t)n * 64;
    const float2 f0 = *(const float2*)ep;
    const float2 f1 = *(const float2*)(ep + 262144);
    u16x2 qw = {f2b(qe * f0.x - qot * f1.x), f2b(qot * f0.y + qe * f1.y)};
    u16x2 kw = {f2b(ke * f0.x - kot * f1.x), f2b(kot * f0.y + ke * f1.y)};
    u16x2 vw = {vbe, vbo};
    const size_t ob = row * 1024 + h * 64 + ip * 2;
    *(u16x2*)(qo + ob) = qw;
    *(u16x2*)(ko + ob) = kw;
    *(u16x2*)(vo + ob) = vw;
  }
}

// per-head V transpose: in [8192][in_ld] bf16 -> out [64 problems][64 d][2048 n]
__global__ __launch_bounds__(256) void vtrans(const u16* __restrict__ in, int in_ld,
                                              int col_off, u16* __restrict__ out) {
  const int p = blockIdx.x, nt = blockIdx.y;
  const int bdb = p >> 4, h = p & 15;
  const int t = threadIdx.x;
  __shared__ __align__(16) u16 tile[64][72];
  {
    const int nl = t >> 2, dc = (t & 3) * 16;
    const u16* sp = in + (size_t)(bdb * 2048 + nt * 64 + nl) * in_ld + col_off + h * 64 + dc;
    u16x8 a = *(const u16x8*)sp;
    u16x8 b = *(const u16x8*)(sp + 8);
#pragma unroll
    for (int j = 0; j < 8; ++j) { tile[nl][dc + j] = a[j]; tile[nl][dc + 8 + j] = b[j]; }
  }
  __syncthreads();
  {
    const int d = t >> 2, nc = (t & 3) * 16;
    u16x8 o0, o1;
#pragma unroll
    for (int j = 0; j < 8; ++j) { o0[j] = tile[nc + j][d]; o1[j] = tile[nc + 8 + j][d]; }
    u16* dp = out + (size_t)p * 131072 + (size_t)d * 2048 + nt * 64 + nc;
    *(u16x8*)dp = o0;
    *(u16x8*)(dp + 8) = o1;
  }
}

// ---------------------------------------------------------------------------
// Flash attention, HD=64, N=2048, scale=1/8.  4 waves x 32 q-rows, KVBLK=64.
// Swapped operands: S = mfma(K,Q); softmax in-register; P via cvt_pk +
// permlane32_swap; O^T = mfma(V^T, P).  K/V double-buffered, XOR-swizzled LDS.
// ---------------------------------------------------------------------------
__global__ __launch_bounds__(256) void attn_fa(const u16* __restrict__ qbase, int q_ld,
                                               const u16* __restrict__ kbase, int k_ld,
                                               const u16* __restrict__ vtbase,
                                               u16* __restrict__ ctxbase, int mode) {
  const int qb = blockIdx.x;  // 0..15
  const int p = blockIdx.y;   // 0..63
  const int t = threadIdx.x, w = t >> 6, l = t & 63;
  const int lq = l & 31;
  const int hi = l >> 5;
  const int hi8 = hi * 8;

  const u16 *qp, *kp, *vtp;
  u16* op;
  if (mode == 0) {
    const int bdb = p >> 4, h = p & 15;
    const size_t rb = (size_t)bdb * 2048;
    qp = qbase + rb * q_ld + h * 64;
    kp = kbase + rb * k_ld + h * 64;
    vtp = vtbase + (size_t)p * 131072;
    op = ctxbase + rb * 1024 + h * 64;
  } else {
    const int bd = p >> 5, b = (p >> 4) & 1, h = p & 15;
    const size_t qrb = (size_t)bd * 4096 + (size_t)b * 2048;
    const size_t krb = (size_t)(1 - bd) * 4096 + (size_t)b * 2048;
    qp = qbase + qrb * q_ld + h * 64;
    kp = kbase + krb * k_ld + h * 64;
    const int pv = ((1 - bd) * 2 + b) * 16 + h;
    vtp = vtbase + (size_t)pv * 131072;
    op = ctxbase + qrb * 1024 + h * 64;
  }

  __shared__ __align__(16) u16 kbuf[2][64 * 64];
  __shared__ __align__(16) u16 vbuf[2][64 * 64];

  const int qrow = qb * 128 + w * 32 + lq;
  bf16x8 qf[4];
#pragma unroll
  for (int dc = 0; dc < 4; ++dc)
    qf[dc] = *(const bf16x8*)(qp + (size_t)qrow * q_ld + dc * 16 + hi8);

  f32x16 accO0 = {}, accO1 = {};
  float m2 = -1e30f, lrun = 0.f;
  const float SC = 0.18033688011116044f;  // 0.125 * log2(e)

  const int sr0 = t >> 3;
  const int sc8 = ((t & 7) ^ (sr0 & 7)) * 8;
  const int ldst = sr0 * 64 + (t & 7) * 8;
  const int swz = (lq & 7) << 3;

  gload16(kp + (size_t)sr0 * k_ld + sc8, &kbuf[0][ldst]);
  gload16(kp + (size_t)(sr0 + 32) * k_ld + sc8, &kbuf[0][ldst + 2048]);
  gload16(vtp + (size_t)sr0 * 2048 + sc8, &vbuf[0][ldst]);
  gload16(vtp + (size_t)(sr0 + 32) * 2048 + sc8, &vbuf[0][ldst + 2048]);
  __syncthreads();

  for (int it = 0; it < 32; ++it) {
    const int cur = it & 1;
    if (it < 31) {
      const int kt = (it + 1) * 64;
      u16* kd = &kbuf[cur ^ 1][ldst];
      u16* vd = &vbuf[cur ^ 1][ldst];
      gload16(kp + (size_t)(kt + sr0) * k_ld + sc8, kd);
      gload16(kp + (size_t)(kt + sr0 + 32) * k_ld + sc8, kd + 2048);
      gload16(vtp + (size_t)sr0 * 2048 + kt + sc8, vd);
      gload16(vtp + (size_t)(sr0 + 32) * 2048 + kt + sc8, vd + 2048);
    }
    const u16* kb = kbuf[cur];
    const u16* vb = vbuf[cur];

    f32x16 s0 = {}, s1 = {};
    __builtin_amdgcn_s_setprio(1);
#pragma unroll
    for (int dc = 0; dc < 4; ++dc) {
      const int off = (dc * 16 + hi8) ^ swz;
      const bf16x8 ka0 = *(const bf16x8*)&kb[lq * 64 + off];
      const bf16x8 ka1 = *(const bf16x8*)&kb[(lq + 32) * 64 + off];
      s0 = MFMA32(ka0, qf[dc], s0);
      s1 = MFMA32(ka1, qf[dc], s1);
    }
    __builtin_amdgcn_s_setprio(0);

    float tm[8];
#pragma unroll
    for (int j = 0; j < 8; ++j)
      tm[j] = fmaxf(fmaxf(s0[j], s0[j + 8]), fmaxf(s1[j], s1[j + 8]));
    float mr = fmaxf(fmaxf(fmaxf(tm[0], tm[1]), fmaxf(tm[2], tm[3])),
                     fmaxf(fmaxf(tm[4], tm[5]), fmaxf(tm[6], tm[7])));
    mr = fmaxf(mr, __shfl_xor(mr, 32));
    const float m2new = fmaxf(m2, mr * SC);
    const float al = __builtin_amdgcn_exp2f(m2 - m2new);
    m2 = m2new;
    f32x16 p0, p1;
#pragma unroll
    for (int r = 0; r < 16; ++r) p0[r] = __builtin_amdgcn_exp2f(fmaf(s0[r], SC, -m2new));
#pragma unroll
    for (int r = 0; r < 16; ++r) p1[r] = __builtin_amdgcn_exp2f(fmaf(s1[r], SC, -m2new));
    const f32x16 ts = p0 + p1;
    float sa[8];
#pragma unroll
    for (int j = 0; j < 8; ++j) sa[j] = ts[j] + ts[j + 8];
    float rs = ((sa[0] + sa[1]) + (sa[2] + sa[3])) + ((sa[4] + sa[5]) + (sa[6] + sa[7]));
    rs += __shfl_xor(rs, 32);
    lrun = lrun * al + rs;
    accO0 *= al;
    accO1 *= al;

    bf16x8 paf[4];
#pragma unroll
    for (int kc = 0; kc < 4; ++kc) {
      const f32x16& ps = (kc < 2) ? p0 : p1;
      const int b0 = (kc & 1) * 8;
      u32 a = cvtpk(ps[b0 + 0], ps[b0 + 1]);
      u32 c = cvtpk(ps[b0 + 2], ps[b0 + 3]);
      u32 b = cvtpk(ps[b0 + 4], ps[b0 + 5]);
      u32 d = cvtpk(ps[b0 + 6], ps[b0 + 7]);
      asm("v_permlane32_swap_b32 %0, %1" : "+v"(a), "+v"(b));
      asm("v_permlane32_swap_b32 %0, %1" : "+v"(c), "+v"(d));
      u32x4 wv = {a, c, b, d};
      paf[kc] = __builtin_bit_cast(bf16x8, wv);
    }

    __builtin_amdgcn_s_setprio(1);
#pragma unroll
    for (int kc = 0; kc < 4; ++kc) {
      const int off = (kc * 16 + hi8) ^ swz;
      const bf16x8 va0 = *(const bf16x8*)&vb[lq * 64 + off];
      const bf16x8 va1 = *(const bf16x8*)&vb[(lq + 32) * 64 + off];
      accO0 = MFMA32(va0, paf[kc], accO0);
      accO1 = MFMA32(va1, paf[kc], accO1);
    }
    __builtin_amdgcn_s_setprio(0);
    __syncthreads();
  }

  const float inv = 1.f / lrun;
  accO0 *= inv;
  accO1 *= inv;
  u16* orow = op + (size_t)qrow * 1024;
#pragma unroll
  for (int r = 0; r < 16; r += 2) {
    const int d = (r & 3) + 8 * (r >> 2) + 4 * hi;
    *(u32*)&orow[d] = cvtpk(accO0[r], accO0[r + 1]);
    *(u32*)&orow[d + 32] = cvtpk(accO1[r], accO1[r + 1]);
  }
}

// ---------------------------------------------------------------------------
// LayerNorm (over 2048) + exact GELU, bf16 in -> bf16 out (stats in fp32)
// ---------------------------------------------------------------------------
__global__ __launch_bounds__(256) void ln_gelu(const u16* __restrict__ H,
                                               const float* __restrict__ gam,
                                               const float* __restrict__ bet,
                                               u16* __restrict__ G) {
  const int row = blockIdx.x, t = threadIdx.x;
  u16x8 hv = *(const u16x8*)(H + (size_t)row * 2048 + t * 8);
  float v[8];
#pragma unroll
  for (int j = 0; j < 8; ++j) v[j] = b2f(hv[j]);
  float s = 0.f, s2 = 0.f;
#pragma unroll
  for (int j = 0; j < 8; ++j) { s += v[j]; s2 += v[j] * v[j]; }
#pragma unroll
  for (int off = 32; off; off >>= 1) { s += __shfl_xor(s, off); s2 += __shfl_xor(s2, off); }
  __shared__ float red[8];
  const int w = t >> 6, l = t & 63;
  if (l == 0) { red[w] = s; red[4 + w] = s2; }
  __syncthreads();
  s = red[0] + red[1] + red[2] + red[3];
  s2 = red[4] + red[5] + red[6] + red[7];
  const float mean = s * (1.f / 2048.f);
  const float rstd = rsqrtf(s2 * (1.f / 2048.f) - mean * mean + 1e-5f);
  u16x8 o;
#pragma unroll
  for (int j = 0; j < 8; ++j) {
    const int col = t * 8 + j;
    const float x = (v[j] - mean) * rstd * gam[col] + bet[col];
    o[j] = f2b(x * 0.5f * (1.f + erff(x * 0.7071067811865475f)));
  }
  *(u16x8*)(G + (size_t)row * 2048 + t * 8) = o;
}

// ---------------------------------------------------------------------------
extern "C" void kernel_launch(void* const* d_in, const int* in_sizes, int n_in,
                              void* d_out, int out_size, void* d_ws, size_t ws_size,
                              hipStream_t stream) {
  (void)in_sizes; (void)n_in; (void)out_size; (void)ws_size;
  const float* desc0 = (const float*)d_in[0];
  const float* desc1 = (const float*)d_in[1];
  const float* enc0 = (const float*)d_in[2];
  const float* enc1 = (const float*)d_in[3];
  const float* wqkv_w = (const float*)d_in[4];
  const float* wqkv_b = (const float*)d_in[5];
  const float* sout_w = (const float*)d_in[6];
  const float* sout_b = (const float*)d_in[7];
  const float* sf1_w = (const float*)d_in[8];
  const float* sf1_b = (const float*)d_in[9];
  const float* sln_g = (const float*)d_in[10];
  const float* sln_b = (const float*)d_in[11];
  const float* sf2_w = (const float*)d_in[12];
  const float* sf2_b = (const float*)d_in[13];
  const float* qk_w = (const float*)d_in[14];
  const float* qk_b = (const float*)d_in[15];
  const float* v_w = (const float*)d_in[16];
  const float* v_b = (const float*)d_in[17];
  const float* cout_w = (const float*)d_in[18];
  const float* cout_b = (const float*)d_in[19];
  const float* cf1_w = (const float*)d_in[20];
  const float* cf1_b = (const float*)d_in[21];
  const float* cln_g = (const float*)d_in[22];
  const float* cln_b = (const float*)d_in[23];
  const float* cf2_w = (const float*)d_in[24];
  const float* cf2_b = (const float*)d_in[25];

  char* ws = (char*)d_ws;
  size_t off = 0;
  auto alloc = [&](size_t n) { char* r = ws + off; off += (n + 255) & ~(size_t)255; return r; };
  // weights (bf16, transposed) — 38 MiB
  u16* wqkv_t = (u16*)alloc((size_t)3072 * 1024 * 2);
  u16* sout_t = (u16*)alloc((size_t)1024 * 1024 * 2);
  u16* sf1_t = (u16*)alloc((size_t)2048 * 2048 * 2);
  u16* sf2_t = (u16*)alloc((size_t)1024 * 2048 * 2);
  u16* wcat_t = (u16*)alloc((size_t)2048 * 1024 * 2);
  u16* cout_t = (u16*)alloc((size_t)1024 * 1024 * 2);
  u16* cf1_t = (u16*)alloc((size_t)2048 * 2048 * 2);
  u16* cf2_t = (u16*)alloc((size_t)1024 * 2048 * 2);
  float* biascat = (float*)alloc(2048 * 4);
  // activations
  u16* CATb = (u16*)alloc((size_t)8192 * 2048 * 2);   // 32 MiB  [x | msg]
  char* BIG = alloc((size_t)8192 * 3072 * 2);         // 48 MiB  QKVbf / Hbf / CQKV
  char* QKB = alloc((size_t)3 * 8192 * 1024 * 2);     // 48 MiB  q,k,v ; G / CTX overlays
  u16* VT = (u16*)alloc((size_t)64 * 64 * 2048 * 2);  // 16 MiB

  u16* QKVbf = (u16*)BIG;
  u16* Hbf = (u16*)BIG;
  u16* CQKV = (u16*)BIG;
  u16* qB = (u16*)QKB;
  u16* kB = qB + (size_t)8192 * 1024;
  u16* vB = kB + (size_t)8192 * 1024;
  u16* G = (u16*)QKB;
  u16* CTX = vB;
  float* OUT = (float*)d_out;

  hipStream_t st = stream;
  // weight prep
  wtrans<<<dim3(48, 16), 256, 0, st>>>(wqkv_w, wqkv_t, 1024, 3072);
  wtrans<<<dim3(16, 16), 256, 0, st>>>(sout_w, sout_t, 1024, 1024);
  wtrans<<<dim3(32, 32), 256, 0, st>>>(sf1_w, sf1_t, 2048, 2048);
  wtrans<<<dim3(16, 32), 256, 0, st>>>(sf2_w, sf2_t, 2048, 1024);
  wtrans<<<dim3(16, 16), 256, 0, st>>>(qk_w, wcat_t, 1024, 1024);
  wtrans<<<dim3(16, 16), 256, 0, st>>>(v_w, wcat_t + (size_t)1024 * 1024, 1024, 1024);
  wtrans<<<dim3(16, 16), 256, 0, st>>>(cout_w, cout_t, 1024, 1024);
  wtrans<<<dim3(32, 32), 256, 0, st>>>(cf1_w, cf1_t, 2048, 2048);
  wtrans<<<dim3(16, 32), 256, 0, st>>>(cf2_w, cf2_t, 2048, 1024);
  bias_cat2<<<8, 256, 0, st>>>(qk_b, v_b, biascat);
  prep_x<<<8192, 256, 0, st>>>(desc0, desc1, CATb);

  // ---- self blocks (batched desc0+desc1) ----
  gemm8<256, 0, 1, 0><<<dim3(12, 32), 512, 0, st>>>(CATb, 2048, wqkv_t, 1024, wqkv_b,
                                                    1024, nullptr, 0, QKVbf, 3072, 0,
                                                    nullptr, nullptr, 1 << 30, 0);
  rope_split<<<dim3(64, 16), 256, 0, st>>>(QKVbf, enc0, enc1, qB, kB, vB);
  vtrans<<<dim3(64, 32), 256, 0, st>>>(vB, 1024, 0, VT);
  attn_fa<<<dim3(16, 64), 256, 0, st>>>(qB, 1024, kB, 1024, VT, CTX, 0);
  gemm8<128, 0, 1, 0><<<dim3(8, 32), 512, 0, st>>>(CTX, 1024, sout_t, 1024, sout_b,
                                                   1024, nullptr, 0, CATb, 2048, 1024,
                                                   nullptr, nullptr, 1 << 30, 0);
  gemm8<256, 0, 1, 0><<<dim3(8, 32), 512, 0, st>>>(CATb, 2048, sf1_t, 2048, sf1_b,
                                                   2048, nullptr, 0, Hbf, 2048, 0,
                                                   nullptr, nullptr, 1 << 30, 0);
  ln_gelu<<<8192, 256, 0, st>>>(Hbf, sln_g, sln_b, G);
  gemm8<128, 1, 1, 1><<<dim3(8, 32), 512, 0, st>>>(G, 2048, sf2_t, 2048, sf2_b, 2048,
                                                   OUT, 1024, CATb, 2048, 0, desc0,
                                                   desc1, 4096, 1024);

  // ---- cross block ----
  gemm8<256, 0, 1, 0><<<dim3(8, 32), 512, 0, st>>>(CATb, 2048, wcat_t, 1024, biascat,
                                                   1024, nullptr, 0, CQKV, 2048, 0,
                                                   nullptr, nullptr, 1 << 30, 0);
  vtrans<<<dim3(64, 32), 256, 0, st>>>(CQKV, 2048, 1024, VT);
  attn_fa<<<dim3(16, 64), 256, 0, st>>>(CQKV, 2048, CQKV, 2048, VT, CTX, 1);
  gemm8<128, 0, 1, 0><<<dim3(8, 32), 512, 0, st>>>(CTX, 1024, cout_t, 1024, cout_b,
                                                   1024, nullptr, 0, CATb, 2048, 1024,
                                                   nullptr, nullptr, 1 << 30, 0);
  gemm8<256, 0, 1, 0><<<dim3(8, 32), 512, 0, st>>>(CATb, 2048, cf1_t, 2048, cf1_b,
                                                   2048, nullptr, 0, Hbf, 2048, 0,
                                                   nullptr, nullptr, 1 << 30, 0);
  ln_gelu<<<8192, 256, 0, st>>>(Hbf, cln_g, cln_b, G);
  gemm8<128, 1, 0, 1><<<dim3(8, 32), 512, 0, st>>>(G, 2048, cf2_t, 2048, cf2_b, 2048,
                                                   OUT, 1024, nullptr, 0, 0, OUT, OUT,
                                                   1 << 30, 1024);
}